// Round 11
// baseline (944.150 us; speedup 1.0000x reference)
//
#include <hip/hip_runtime.h>
#include <hip/hip_bf16.h>

typedef __bf16 bf16;
typedef __bf16 bf16x8 __attribute__((ext_vector_type(8)));
typedef __bf16 bf16x4 __attribute__((ext_vector_type(4)));
typedef float f32x4_t __attribute__((ext_vector_type(4)));

static constexpr int kDIM = 512;

// ---------------- ws layout (bytes) ----------------
static constexpr size_t OFF_QKVW = 0;                         // 1536*512 bf16
static constexpr size_t OFF_PROJW = 1572864;                  // 512*512 bf16
static constexpr size_t OFF_W1   = 2097152;                   // 2048*512 bf16
static constexpr size_t OFF_W2   = 4194304;                   // 512*2048 bf16
static constexpr size_t OFF_PTAB = 6291456;                   // 225*16 f32
static constexpr size_t OFF_A    = 8388608;                   // qkv / hidden bf16
static constexpr size_t OFF_B    = 276824064;                 // h / o / ln2out bf16

typedef __attribute__((address_space(3))) uint32_t lds_u32_t;
typedef __attribute__((address_space(1))) const uint32_t glb_u32_t;
#define ASYNC_COPY16(gp, lp) __builtin_amdgcn_global_load_lds((glb_u32_t*)(gp), (lds_u32_t*)(lp), 16, 0, 0)

// raw barrier with compiler memory fence (NOT __syncthreads: that re-adds vmcnt(0) drain)
#define BARR()                                   \
    do {                                         \
        asm volatile("" ::: "memory");           \
        __builtin_amdgcn_s_barrier();            \
        asm volatile("" ::: "memory");           \
    } while (0)

// ---------------- fp32 -> bf16 cast ----------------
__global__ void cast_bf16_k(const float* __restrict__ in, bf16* __restrict__ out, int n4)
{
    int i = blockIdx.x * blockDim.x + threadIdx.x;
    if (i < n4) {
        float4 v = ((const float4*)in)[i];
        bf16x4 o; o[0] = (bf16)v.x; o[1] = (bf16)v.y; o[2] = (bf16)v.z; o[3] = (bf16)v.w;
        ((bf16x4*)out)[i] = o;
    }
}

// ---------------- LayerNorm (+ optional LDA grouping) -> bf16 ----------------
template<int GROUP>
__global__ __launch_bounds__(256)
void ln_k(const float* __restrict__ x, const float* __restrict__ gw,
          const float* __restrict__ bw, bf16* __restrict__ out)
{
    const int t = blockIdx.x * 4 + (threadIdx.x >> 6);
    const int lane = threadIdx.x & 63;
    const float* xp = x + (size_t)t * kDIM + lane * 8;
    float4 p0 = *(const float4*)xp;
    float4 p1 = *(const float4*)(xp + 4);
    float v[8] = {p0.x, p0.y, p0.z, p0.w, p1.x, p1.y, p1.z, p1.w};
    float s = 0.f;
#pragma unroll
    for (int i = 0; i < 8; ++i) s += v[i];
#pragma unroll
    for (int off = 32; off > 0; off >>= 1) s += __shfl_xor(s, off);
    const float mean = s * (1.0f / 512.0f);
    float q = 0.f;
#pragma unroll
    for (int i = 0; i < 8; ++i) { float d = v[i] - mean; q += d * d; }
#pragma unroll
    for (int off = 32; off > 0; off >>= 1) q += __shfl_xor(q, off);
    const float rstd = rsqrtf(q * (1.0f / 512.0f) + 1e-5f);
    size_t orow;
    if (GROUP) {
        int b = t >> 12, r = (t >> 6) & 63, c = t & 63;
        int g = b * 64 + (r & 7) * 8 + (c & 7);
        int n = (r >> 3) * 8 + (c >> 3);
        orow = (size_t)g * 64 + n;
    } else {
        orow = t;
    }
    float4 g0 = *(const float4*)(gw + lane * 8);
    float4 g1 = *(const float4*)(gw + lane * 8 + 4);
    float4 b0 = *(const float4*)(bw + lane * 8);
    float4 b1 = *(const float4*)(bw + lane * 8 + 4);
    float gg[8] = {g0.x, g0.y, g0.z, g0.w, g1.x, g1.y, g1.z, g1.w};
    float bb[8] = {b0.x, b0.y, b0.z, b0.w, b1.x, b1.y, b1.z, b1.w};
    bf16x8 o8;
#pragma unroll
    for (int i = 0; i < 8; ++i) o8[i] = (bf16)((v[i] - mean) * rstd * gg[i] + bb[i]);
    *(bf16x8*)(out + orow * kDIM + lane * 8) = o8;
}

// ---------------- dynamic position bias MLP: 225 rows, 2->32->32->32->16 ----------------
__device__ inline void ln32_relu(float* h, const float* g, const float* b)
{
    float m = 0.f;
#pragma unroll
    for (int i = 0; i < 32; ++i) m += h[i];
    m *= (1.0f / 32.0f);
    float v = 0.f;
#pragma unroll
    for (int i = 0; i < 32; ++i) { float d = h[i] - m; v += d * d; }
    v *= (1.0f / 32.0f);
    float r = rsqrtf(v + 1e-5f);
#pragma unroll
    for (int i = 0; i < 32; ++i) h[i] = fmaxf((h[i] - m) * r * g[i] + b[i], 0.f);
}

__global__ __launch_bounds__(256)
void posmlp_k(const float* __restrict__ w0, const float* __restrict__ b0,
              const float* __restrict__ g0, const float* __restrict__ bb0,
              const float* __restrict__ w1, const float* __restrict__ b1,
              const float* __restrict__ g1, const float* __restrict__ bb1,
              const float* __restrict__ w2, const float* __restrict__ b2,
              const float* __restrict__ g2, const float* __restrict__ bb2,
              const float* __restrict__ w3, const float* __restrict__ b3,
              float* __restrict__ ptab)
{
    int r = threadIdx.x;
    if (r >= 225) return;
    float in0 = (float)(r / 15) - 7.0f;
    float in1 = (float)(r % 15) - 7.0f;
    float h[32], h2[32];
#pragma unroll
    for (int o = 0; o < 32; ++o) h[o] = w0[o * 2] * in0 + w0[o * 2 + 1] * in1 + b0[o];
    ln32_relu(h, g0, bb0);
#pragma unroll
    for (int o = 0; o < 32; ++o) {
        float s = b1[o];
#pragma unroll
        for (int i = 0; i < 32; ++i) s += w1[o * 32 + i] * h[i];
        h2[o] = s;
    }
    ln32_relu(h2, g1, bb1);
#pragma unroll
    for (int o = 0; o < 32; ++o) {
        float s = b2[o];
#pragma unroll
        for (int i = 0; i < 32; ++i) s += w2[o * 32 + i] * h2[i];
        h[o] = s;
    }
    ln32_relu(h, g2, bb2);
#pragma unroll
    for (int o = 0; o < 16; ++o) {
        float s = b3[o];
#pragma unroll
        for (int i = 0; i < 32; ++i) s += w3[o * 32 + i] * h[i];
        ptab[r * 16 + o] = s;
    }
}

// ---------------- attention via MFMA: block = (group, head-octet), 4 waves x 2 heads ----------------
// V path: coalesced 16B row loads -> per-wave XOR-swizzled LDS V^T -> b128 B-frag reads.
__global__ __launch_bounds__(256)
void attn_mfma_k(const bf16* __restrict__ qkv, const float* __restrict__ ptab,
                 bf16* __restrict__ obuf)
{
    const int g  = blockIdx.x >> 1;
    const int hb = blockIdx.x & 1;
    const int w  = threadIdx.x >> 6;
    const int lane = threadIdx.x & 63;
    const int c = lane & 15, q = lane >> 4;

    __shared__ float ptl[16][240];                 // ptab transposed [head][idx]
    __shared__ alignas(16) bf16 pl[4][4096];       // per-wave P (64x64), XOR-swizzled
    __shared__ alignas(16) bf16 vt[4][2048];       // per-wave V^T (32 d x 64 m), swizzled

    for (int i = threadIdx.x; i < 3600; i += 256)
        ptl[i & 15][i >> 4] = ptab[i];
    __syncthreads();

    const size_t rowb = (size_t)g * 64;
    bf16* pw = pl[w];
    char* vw = (char*)vt[w];

    for (int hh = 0; hh < 2; ++hh) {
        const int head = hb * 8 + hh * 4 + w;
        const bf16* qb = qkv + rowb * 1536 + head * 32;

        // V rows: coalesced 16B loads (issued first; land under QK^T)
        bf16x8 vrow[4];
#pragma unroll
        for (int l = 0; l < 4; ++l)
            vrow[l] = *(const bf16x8*)(qb + 1024 + (size_t)lane * 1536 + l * 8);

        // Q A-frags, K B-frags (16B/lane)
        bf16x8 aq[4], bk[4];
#pragma unroll
        for (int i = 0; i < 4; ++i) {
            aq[i] = *(const bf16x8*)(qb + (size_t)(i * 16 + c) * 1536 + q * 8);
            bk[i] = *(const bf16x8*)(qb + 512 + (size_t)(i * 16 + c) * 1536 + q * 8);
        }

        // S = Q K^T
        f32x4_t s[4][4];
#pragma unroll
        for (int i = 0; i < 4; ++i)
#pragma unroll
            for (int j = 0; j < 4; ++j)
                s[i][j] = __builtin_amdgcn_mfma_f32_16x16x32_bf16(aq[i], bk[j],
                          (f32x4_t){0.f, 0.f, 0.f, 0.f}, 0, 0, 0);

        // V^T -> LDS (row d, offset m*2 XOR (d&7)<<4)
#pragma unroll
        for (int l = 0; l < 4; ++l)
#pragma unroll
            for (int j = 0; j < 8; ++j) {
                const int d = l * 8 + j;
                *(bf16*)(vw + d * 128 + ((lane * 2) ^ ((d & 7) << 4))) = vrow[l][j];
            }

        // scale + rel-pos bias + row softmax
        const float scale = 0.17677669529663687f;  // 1/sqrt(32)
        float inv[4][4];
#pragma unroll
        for (int i = 0; i < 4; ++i)
#pragma unroll
            for (int jj = 0; jj < 4; ++jj) {
                const int n = i * 16 + q * 4 + jj;
                const int na = n >> 3, nu = n & 7;
                float mx = -1e30f;
#pragma unroll
                for (int j = 0; j < 4; ++j) {
                    const int m = j * 16 + c;
                    const int idx = (na - (m >> 3) + 7) * 15 + (nu - (m & 7) + 7);
                    float v = s[i][j][jj] * scale + ptl[head][idx];
                    s[i][j][jj] = v;
                    mx = fmaxf(mx, v);
                }
#pragma unroll
                for (int off = 1; off < 16; off <<= 1) mx = fmaxf(mx, __shfl_xor(mx, off));
                float sum = 0.f;
#pragma unroll
                for (int j = 0; j < 4; ++j) {
                    float e = __expf(s[i][j][jj] - mx);
                    s[i][j][jj] = e; sum += e;
                }
#pragma unroll
                for (int off = 1; off < 16; off <<= 1) sum += __shfl_xor(sum, off);
                inv[i][jj] = 1.0f / sum;
            }

        // P -> LDS (bf16, swizzled: byte ^= (row&7)<<4)
#pragma unroll
        for (int i = 0; i < 4; ++i)
#pragma unroll
            for (int jj = 0; jj < 4; ++jj) {
                const int n = i * 16 + q * 4 + jj;
                const int swz = (n & 7) << 4;
#pragma unroll
                for (int j = 0; j < 4; ++j) {
                    const int m = j * 16 + c;
                    *(bf16*)((char*)pw + n * 128 + ((m * 2) ^ swz)) = (bf16)s[i][j][jj];
                }
            }

        // V B-frags from LDS V^T
        bf16x8 bv[2][2];
#pragma unroll
        for (int ks = 0; ks < 2; ++ks)
#pragma unroll
            for (int dt = 0; dt < 2; ++dt)
                bv[ks][dt] = *(const bf16x8*)(vw + (dt * 16 + c) * 128 +
                              ((ks * 64 + q * 16) ^ ((c & 7) << 4)));

        // O = P V
        f32x4_t o[4][2];
#pragma unroll
        for (int i = 0; i < 4; ++i)
#pragma unroll
            for (int dt = 0; dt < 2; ++dt)
                o[i][dt] = (f32x4_t){0.f, 0.f, 0.f, 0.f};
#pragma unroll
        for (int ks = 0; ks < 2; ++ks)
#pragma unroll
            for (int i = 0; i < 4; ++i) {
                const int n = i * 16 + c;
                bf16x8 ap = *(const bf16x8*)((char*)pw + n * 128 +
                             ((ks * 64 + q * 16) ^ ((n & 7) << 4)));
#pragma unroll
                for (int dt = 0; dt < 2; ++dt)
                    o[i][dt] = __builtin_amdgcn_mfma_f32_16x16x32_bf16(ap, bv[ks][dt], o[i][dt], 0, 0, 0);
            }

        // normalize + store
        bf16* ob = obuf + rowb * 512 + head * 32;
#pragma unroll
        for (int i = 0; i < 4; ++i)
#pragma unroll
            for (int dt = 0; dt < 2; ++dt)
#pragma unroll
                for (int jj = 0; jj < 4; ++jj) {
                    const int n = i * 16 + q * 4 + jj;
                    ob[(size_t)n * 512 + dt * 16 + c] = (bf16)(o[i][dt][jj] * inv[i][jj]);
                }
    }
}

// ---------------- GEMM: C[M,N] = A[M,K] * Bw[N,K]^T + bias ----------------
// 128x128 tile, BK=32, DOUBLE-buffered at 32 KiB total (same LDS footprint as the
// proven R7 single-buffer -> ~5 blocks/CU TLP retained) + T4 counted vmcnt:
// per iter {vmcnt(4): tile t landed, tile t+1's 4 loads stay in flight; barrier;
// 8 ds_read + 16 MFMA from buf[t&1]; barrier; stage tile t+2 into buf[t&1]}.
// Raw s_barrier (not __syncthreads) so no implicit vmcnt(0) drain is re-inserted.
// Rows are 64B (BK=32): swizzle slot s -> s^(row&3) on the global source; read
// offset = (q ^ (row&3))*16 -> full-wave b128 read covers all 32 banks in the
// minimum 8 rounds (conflict-free; R6 counters confirmed 0 for this swizzle).
// T1: XCD-aware bijective block swizzle (all grids have nwg % 8 == 0).
// MODE 0: +bias -> bf16 (QKV) | 1: +bias,gelu -> bf16 (MLP1)
// MODE 2: +bias +x, ungroup -> f32 (proj) | 3: +bias +resid -> f32 (MLP2)
#define STAGE_T(Ad, Bd, ktv)                                                              \
    do {                                                                                  \
        _Pragma("unroll")                                                                 \
        for (int l_ = 0; l_ < 2; ++l_) {                                                  \
            const int cg_ = l_ * 256 + tid;                                               \
            const int row_ = cg_ >> 2;                                                    \
            const int s_ = (cg_ & 3) ^ (row_ & 3);                                        \
            const int cu_ = l_ * 256 + (tid & 192);                                       \
            ASYNC_COPY16(A + (size_t)(rowBase + row_) * K + (ktv) + s_ * 8, (Ad) + cu_ * 8); \
            ASYNC_COPY16(Bw + (size_t)(colBase + row_) * K + (ktv) + s_ * 8, (Bd) + cu_ * 8); \
        }                                                                                 \
    } while (0)

template<int MODE, int NBX>
__global__ __launch_bounds__(256, 2)
void gemm_bt(const bf16* __restrict__ A, const bf16* __restrict__ Bw,
             const float* __restrict__ bias, const float* __restrict__ resid,
             bf16* __restrict__ outb, float* __restrict__ outf,
             int N, int K)
{
    __shared__ alignas(16) bf16 As[2][128 * 32];   // 2 x 8 KiB
    __shared__ alignas(16) bf16 Bs[2][128 * 32];   // 2 x 8 KiB
    const int tid = threadIdx.x;
    const int lane = tid & 63;
    const int w = tid >> 6;
    const int wr = w >> 1, wc = w & 1;

    // T1: XCD swizzle, bijective since nwg % 8 == 0
    const int bid = blockIdx.y * NBX + blockIdx.x;
    const int nwg = gridDim.y * NBX;
    const int swz = (bid & 7) * (nwg >> 3) + (bid >> 3);
    const int by = swz / NBX;
    const int bx = swz - by * NBX;
    const int rowBase = by * 128;
    const int colBase = bx * 128;

    f32x4_t acc[4][4];
#pragma unroll
    for (int m = 0; m < 4; ++m)
#pragma unroll
        for (int n = 0; n < 4; ++n)
            acc[m][n] = (f32x4_t){0.f, 0.f, 0.f, 0.f};

    // read byte offset within a 64B row: (q ^ (row&3))*16; row&3 == lane&3
    const int rdofs = (((lane >> 4) ^ (lane & 3)) << 4);
    const int nt = K >> 5;   // BK=32 tiles; >= 16 at all call sites

    STAGE_T(As[0], Bs[0], 0);
    STAGE_T(As[1], Bs[1], 32);

    for (int t = 0; t < nt; ++t) {
        // tile t landed; tile t+1's 4 loads may remain in flight
        if (t + 1 < nt) { asm volatile("s_waitcnt vmcnt(4)" ::: "memory"); }
        else            { asm volatile("s_waitcnt vmcnt(0)" ::: "memory"); }
        BARR();

        const char* Ac = (const char*)As[t & 1];
        const char* Bc = (const char*)Bs[t & 1];
        bf16x8 af[4], bfr[4];
#pragma unroll
        for (int m = 0; m < 4; ++m) {
            const int row = wr * 64 + m * 16 + (lane & 15);
            af[m] = *(const bf16x8*)(Ac + row * 64 + rdofs);
        }
#pragma unroll
        for (int n = 0; n < 4; ++n) {
            const int row = wc * 64 + n * 16 + (lane & 15);
            bfr[n] = *(const bf16x8*)(Bc + row * 64 + rdofs);
        }
#pragma unroll
        for (int m = 0; m < 4; ++m)
#pragma unroll
            for (int n = 0; n < 4; ++n)
                acc[m][n] = __builtin_amdgcn_mfma_f32_16x16x32_bf16(af[m], bfr[n], acc[m][n], 0, 0, 0);

        BARR();   // all reads of buf[t&1] retired -> safe to overwrite
        if (t + 2 < nt) STAGE_T(As[t & 1], Bs[t & 1], (t + 2) << 5);
    }

#pragma unroll
    for (int m = 0; m < 4; ++m) {
#pragma unroll
        for (int jj = 0; jj < 4; ++jj) {
            int grow = rowBase + wr * 64 + m * 16 + (lane >> 4) * 4 + jj;
#pragma unroll
            for (int n = 0; n < 4; ++n) {
                int gcol = colBase + wc * 64 + n * 16 + (lane & 15);
                float v = acc[m][n][jj] + bias[gcol];
                if constexpr (MODE == 0) {
                    outb[(size_t)grow * N + gcol] = (bf16)v;
                } else if constexpr (MODE == 1) {
                    // gelu(v) ~= v * sigmoid(1.5957691*(v + 0.044715 v^3))
                    float e = __expf(1.5957691216057308f * (v + 0.044715f * v * v * v));
                    v = v * (e / (1.0f + e));
                    outb[(size_t)grow * N + gcol] = (bf16)v;
                } else if constexpr (MODE == 2) {
                    int g = grow >> 6, ns = grow & 63;
                    int b = g >> 6, i = (g >> 3) & 7, j = g & 7;
                    int a = ns >> 3, u = ns & 7;
                    int t2 = b * 4096 + (a * 8 + i) * 64 + (u * 8 + j);
                    size_t oi = (size_t)t2 * 512 + gcol;
                    outf[oi] = resid[oi] + v;
                } else {
                    size_t oi = (size_t)grow * 512 + gcol;
                    outf[oi] = resid[oi] + v;
                }
            }
        }
    }
}

// ---------------- launcher ----------------
extern "C" void kernel_launch(void* const* d_in, const int* in_sizes, int n_in,
                              void* d_out, int out_size, void* d_ws, size_t ws_size,
                              hipStream_t stream)
{
    const float* x    = (const float*)d_in[0];
    const float* n1g  = (const float*)d_in[1];
    const float* n1b  = (const float*)d_in[2];
    const float* qkvw = (const float*)d_in[3];
    const float* qkvb = (const float*)d_in[4];
    const float* pjw  = (const float*)d_in[5];
    const float* pjb  = (const float*)d_in[6];
    const float* pw0  = (const float*)d_in[7];
    const float* pb0  = (const float*)d_in[8];
    const float* pg0  = (const float*)d_in[9];
    const float* pbb0 = (const float*)d_in[10];
    const float* pw1  = (const float*)d_in[11];
    const float* pb1  = (const float*)d_in[12];
    const float* pg1  = (const float*)d_in[13];
    const float* pbb1 = (const float*)d_in[14];
    const float* pw2  = (const float*)d_in[15];
    const float* pb2  = (const float*)d_in[16];
    const float* pg2  = (const float*)d_in[17];
    const float* pbb2 = (const float*)d_in[18];
    const float* pw3  = (const float*)d_in[19];
    const float* pb3  = (const float*)d_in[20];
    const float* n2g  = (const float*)d_in[21];
    const float* n2b  = (const float*)d_in[22];
    const float* w1   = (const float*)d_in[23];
    const float* b1   = (const float*)d_in[24];
    const float* w2   = (const float*)d_in[25];
    const float* b2   = (const float*)d_in[26];

    char* ws = (char*)d_ws;
    bf16* qkvw_b = (bf16*)(ws + OFF_QKVW);
    bf16* pjw_b  = (bf16*)(ws + OFF_PROJW);
    bf16* w1_b   = (bf16*)(ws + OFF_W1);
    bf16* w2_b   = (bf16*)(ws + OFF_W2);
    float* ptab  = (float*)(ws + OFF_PTAB);
    bf16* bufA   = (bf16*)(ws + OFF_A);
    bf16* bufB   = (bf16*)(ws + OFF_B);
    float* xout  = (float*)d_out;

    // weight casts
    cast_bf16_k<<<(1536 * 512 / 4 + 255) / 256, 256, 0, stream>>>(qkvw, qkvw_b, 1536 * 512 / 4);
    cast_bf16_k<<<(512 * 512 / 4 + 255) / 256, 256, 0, stream>>>(pjw, pjw_b, 512 * 512 / 4);
    cast_bf16_k<<<(2048 * 512 / 4 + 255) / 256, 256, 0, stream>>>(w1, w1_b, 2048 * 512 / 4);
    cast_bf16_k<<<(512 * 2048 / 4 + 255) / 256, 256, 0, stream>>>(w2, w2_b, 512 * 2048 / 4);

    // pos-bias table
    posmlp_k<<<1, 256, 0, stream>>>(pw0, pb0, pg0, pbb0, pw1, pb1, pg1, pbb1,
                                    pw2, pb2, pg2, pbb2, pw3, pb3, ptab);

    // LN1 + group -> bufB
    ln_k<1><<<16384, 256, 0, stream>>>(x, n1g, n1b, bufB);

    // QKV -> bufA
    gemm_bt<0, 12><<<dim3(12, 512), 256, 0, stream>>>(bufB, qkvw_b, qkvb, nullptr, bufA, nullptr, 1536, 512);

    // attention -> bufB
    attn_mfma_k<<<2048, 256, 0, stream>>>(bufA, ptab, bufB);

    // proj + ungroup + residual(x) -> d_out (x1)
    gemm_bt<2, 4><<<dim3(4, 512), 256, 0, stream>>>(bufB, pjw_b, pjb, x, nullptr, xout, 512, 512);

    // LN2 -> bufB
    ln_k<0><<<16384, 256, 0, stream>>>(xout, n2g, n2b, bufB);

    // MLP1 + gelu -> bufA
    gemm_bt<1, 16><<<dim3(16, 512), 256, 0, stream>>>(bufB, w1_b, b1, nullptr, bufA, nullptr, 2048, 512);

    // MLP2 + residual(x1) -> d_out (in place)
    gemm_bt<3, 4><<<dim3(4, 512), 256, 0, stream>>>(bufA, w2_b, b2, xout, nullptr, xout, 512, 2048);
}

// Round 12
// 814.723 us; speedup vs baseline: 1.1589x; 1.1589x over previous
//
#include <hip/hip_runtime.h>
#include <hip/hip_bf16.h>

typedef __bf16 bf16;
typedef __bf16 bf16x8 __attribute__((ext_vector_type(8)));
typedef __bf16 bf16x4 __attribute__((ext_vector_type(4)));
typedef float f32x4_t __attribute__((ext_vector_type(4)));

static constexpr int kDIM = 512;

// ---------------- ws layout (bytes) ----------------
static constexpr size_t OFF_QKVW = 0;                         // 1536*512 bf16
static constexpr size_t OFF_PROJW = 1572864;                  // 512*512 bf16
static constexpr size_t OFF_W1   = 2097152;                   // 2048*512 bf16
static constexpr size_t OFF_W2   = 4194304;                   // 512*2048 fp8 (1 MB)
static constexpr size_t OFF_PTAB = 6291456;                   // 225*16 f32
static constexpr size_t OFF_A    = 8388608;                   // qkv bf16 / hidden fp8
static constexpr size_t OFF_B    = 276824064;                 // h / o / ln2out bf16

typedef __attribute__((address_space(3))) uint32_t lds_u32_t;
typedef __attribute__((address_space(1))) const uint32_t glb_u32_t;
#define ASYNC_COPY16(gp, lp) __builtin_amdgcn_global_load_lds((glb_u32_t*)(gp), (lds_u32_t*)(lp), 16, 0, 0)
#define WAITV0() asm volatile("s_waitcnt vmcnt(0)" ::: "memory")

// ---------------- fp32 -> bf16 cast ----------------
__global__ void cast_bf16_k(const float* __restrict__ in, bf16* __restrict__ out, int n4)
{
    int i = blockIdx.x * blockDim.x + threadIdx.x;
    if (i < n4) {
        float4 v = ((const float4*)in)[i];
        bf16x4 o; o[0] = (bf16)v.x; o[1] = (bf16)v.y; o[2] = (bf16)v.z; o[3] = (bf16)v.w;
        ((bf16x4*)out)[i] = o;
    }
}

// ---------------- fp32 -> fp8 e4m3 cast with x64 scale ----------------
__global__ void cast_fp8_k(const float* __restrict__ in, unsigned char* __restrict__ out, int n4)
{
    int i = blockIdx.x * blockDim.x + threadIdx.x;
    if (i < n4) {
        float4 v = ((const float4*)in)[i];
        int p = __builtin_amdgcn_cvt_pk_fp8_f32(v.x * 64.0f, v.y * 64.0f, 0, false);
        p = __builtin_amdgcn_cvt_pk_fp8_f32(v.z * 64.0f, v.w * 64.0f, p, true);
        ((unsigned int*)out)[i] = (unsigned int)p;
    }
}

// ---------------- LayerNorm (+ optional LDA grouping) -> bf16 ----------------
template<int GROUP>
__global__ __launch_bounds__(256)
void ln_k(const float* __restrict__ x, const float* __restrict__ gw,
          const float* __restrict__ bw, bf16* __restrict__ out)
{
    const int t = blockIdx.x * 4 + (threadIdx.x >> 6);
    const int lane = threadIdx.x & 63;
    const float* xp = x + (size_t)t * kDIM + lane * 8;
    float4 p0 = *(const float4*)xp;
    float4 p1 = *(const float4*)(xp + 4);
    float v[8] = {p0.x, p0.y, p0.z, p0.w, p1.x, p1.y, p1.z, p1.w};
    float s = 0.f;
#pragma unroll
    for (int i = 0; i < 8; ++i) s += v[i];
#pragma unroll
    for (int off = 32; off > 0; off >>= 1) s += __shfl_xor(s, off);
    const float mean = s * (1.0f / 512.0f);
    float q = 0.f;
#pragma unroll
    for (int i = 0; i < 8; ++i) { float d = v[i] - mean; q += d * d; }
#pragma unroll
    for (int off = 32; off > 0; off >>= 1) q += __shfl_xor(q, off);
    const float rstd = rsqrtf(q * (1.0f / 512.0f) + 1e-5f);
    size_t orow;
    if (GROUP) {
        int b = t >> 12, r = (t >> 6) & 63, c = t & 63;
        int g = b * 64 + (r & 7) * 8 + (c & 7);
        int n = (r >> 3) * 8 + (c >> 3);
        orow = (size_t)g * 64 + n;
    } else {
        orow = t;
    }
    float4 g0 = *(const float4*)(gw + lane * 8);
    float4 g1 = *(const float4*)(gw + lane * 8 + 4);
    float4 b0 = *(const float4*)(bw + lane * 8);
    float4 b1 = *(const float4*)(bw + lane * 8 + 4);
    float gg[8] = {g0.x, g0.y, g0.z, g0.w, g1.x, g1.y, g1.z, g1.w};
    float bb[8] = {b0.x, b0.y, b0.z, b0.w, b1.x, b1.y, b1.z, b1.w};
    bf16x8 o8;
#pragma unroll
    for (int i = 0; i < 8; ++i) o8[i] = (bf16)((v[i] - mean) * rstd * gg[i] + bb[i]);
    *(bf16x8*)(out + orow * kDIM + lane * 8) = o8;
}

// ---------------- dynamic position bias MLP: 225 rows, 2->32->32->32->16 ----------------
__device__ inline void ln32_relu(float* h, const float* g, const float* b)
{
    float m = 0.f;
#pragma unroll
    for (int i = 0; i < 32; ++i) m += h[i];
    m *= (1.0f / 32.0f);
    float v = 0.f;
#pragma unroll
    for (int i = 0; i < 32; ++i) { float d = h[i] - m; v += d * d; }
    v *= (1.0f / 32.0f);
    float r = rsqrtf(v + 1e-5f);
#pragma unroll
    for (int i = 0; i < 32; ++i) h[i] = fmaxf((h[i] - m) * r * g[i] + b[i], 0.f);
}

__global__ __launch_bounds__(256)
void posmlp_k(const float* __restrict__ w0, const float* __restrict__ b0,
              const float* __restrict__ g0, const float* __restrict__ bb0,
              const float* __restrict__ w1, const float* __restrict__ b1,
              const float* __restrict__ g1, const float* __restrict__ bb1,
              const float* __restrict__ w2, const float* __restrict__ b2,
              const float* __restrict__ g2, const float* __restrict__ bb2,
              const float* __restrict__ w3, const float* __restrict__ b3,
              float* __restrict__ ptab)
{
    int r = threadIdx.x;
    if (r >= 225) return;
    float in0 = (float)(r / 15) - 7.0f;
    float in1 = (float)(r % 15) - 7.0f;
    float h[32], h2[32];
#pragma unroll
    for (int o = 0; o < 32; ++o) h[o] = w0[o * 2] * in0 + w0[o * 2 + 1] * in1 + b0[o];
    ln32_relu(h, g0, bb0);
#pragma unroll
    for (int o = 0; o < 32; ++o) {
        float s = b1[o];
#pragma unroll
        for (int i = 0; i < 32; ++i) s += w1[o * 32 + i] * h[i];
        h2[o] = s;
    }
    ln32_relu(h2, g1, bb1);
#pragma unroll
    for (int o = 0; o < 32; ++o) {
        float s = b2[o];
#pragma unroll
        for (int i = 0; i < 32; ++i) s += w2[o * 32 + i] * h2[i];
        h[o] = s;
    }
    ln32_relu(h, g2, bb2);
#pragma unroll
    for (int o = 0; o < 16; ++o) {
        float s = b3[o];
#pragma unroll
        for (int i = 0; i < 32; ++i) s += w3[o * 32 + i] * h[i];
        ptab[r * 16 + o] = s;
    }
}

// ---------------- attention via MFMA: block = (group, head-octet), 4 waves x 2 heads ----------------
__global__ __launch_bounds__(256)
void attn_mfma_k(const bf16* __restrict__ qkv, const float* __restrict__ ptab,
                 bf16* __restrict__ obuf)
{
    const int g  = blockIdx.x >> 1;
    const int hb = blockIdx.x & 1;
    const int w  = threadIdx.x >> 6;
    const int lane = threadIdx.x & 63;
    const int c = lane & 15, q = lane >> 4;

    __shared__ float ptl[16][240];                 // ptab transposed [head][idx]
    __shared__ alignas(16) bf16 pl[4][4096];       // per-wave P (64x64), XOR-swizzled
    __shared__ alignas(16) bf16 vt[4][2048];       // per-wave V^T (32 d x 64 m), swizzled

    for (int i = threadIdx.x; i < 3600; i += 256)
        ptl[i & 15][i >> 4] = ptab[i];
    __syncthreads();

    const size_t rowb = (size_t)g * 64;
    bf16* pw = pl[w];
    char* vw = (char*)vt[w];

    for (int hh = 0; hh < 2; ++hh) {
        const int head = hb * 8 + hh * 4 + w;
        const bf16* qb = qkv + rowb * 1536 + head * 32;

        // V rows: coalesced 16B loads (issued first; land under QK^T)
        bf16x8 vrow[4];
#pragma unroll
        for (int l = 0; l < 4; ++l)
            vrow[l] = *(const bf16x8*)(qb + 1024 + (size_t)lane * 1536 + l * 8);

        // Q A-frags, K B-frags (16B/lane)
        bf16x8 aq[4], bk[4];
#pragma unroll
        for (int i = 0; i < 4; ++i) {
            aq[i] = *(const bf16x8*)(qb + (size_t)(i * 16 + c) * 1536 + q * 8);
            bk[i] = *(const bf16x8*)(qb + 512 + (size_t)(i * 16 + c) * 1536 + q * 8);
        }

        // S = Q K^T
        f32x4_t s[4][4];
#pragma unroll
        for (int i = 0; i < 4; ++i)
#pragma unroll
            for (int j = 0; j < 4; ++j)
                s[i][j] = __builtin_amdgcn_mfma_f32_16x16x32_bf16(aq[i], bk[j],
                          (f32x4_t){0.f, 0.f, 0.f, 0.f}, 0, 0, 0);

        // V^T -> LDS (row d, offset m*2 XOR (d&7)<<4)
#pragma unroll
        for (int l = 0; l < 4; ++l)
#pragma unroll
            for (int j = 0; j < 8; ++j) {
                const int d = l * 8 + j;
                *(bf16*)(vw + d * 128 + ((lane * 2) ^ ((d & 7) << 4))) = vrow[l][j];
            }

        // scale + rel-pos bias + row softmax
        const float scale = 0.17677669529663687f;  // 1/sqrt(32)
        float inv[4][4];
#pragma unroll
        for (int i = 0; i < 4; ++i)
#pragma unroll
            for (int jj = 0; jj < 4; ++jj) {
                const int n = i * 16 + q * 4 + jj;
                const int na = n >> 3, nu = n & 7;
                float mx = -1e30f;
#pragma unroll
                for (int j = 0; j < 4; ++j) {
                    const int m = j * 16 + c;
                    const int idx = (na - (m >> 3) + 7) * 15 + (nu - (m & 7) + 7);
                    float v = s[i][j][jj] * scale + ptl[head][idx];
                    s[i][j][jj] = v;
                    mx = fmaxf(mx, v);
                }
#pragma unroll
                for (int off = 1; off < 16; off <<= 1) mx = fmaxf(mx, __shfl_xor(mx, off));
                float sum = 0.f;
#pragma unroll
                for (int j = 0; j < 4; ++j) {
                    float e = __expf(s[i][j][jj] - mx);
                    s[i][j][jj] = e; sum += e;
                }
#pragma unroll
                for (int off = 1; off < 16; off <<= 1) sum += __shfl_xor(sum, off);
                inv[i][jj] = 1.0f / sum;
            }

        // P -> LDS (bf16, swizzled: byte ^= (row&7)<<4)
#pragma unroll
        for (int i = 0; i < 4; ++i)
#pragma unroll
            for (int jj = 0; jj < 4; ++jj) {
                const int n = i * 16 + q * 4 + jj;
                const int swz = (n & 7) << 4;
#pragma unroll
                for (int j = 0; j < 4; ++j) {
                    const int m = j * 16 + c;
                    *(bf16*)((char*)pw + n * 128 + ((m * 2) ^ swz)) = (bf16)s[i][j][jj];
                }
            }

        // V B-frags from LDS V^T
        bf16x8 bv[2][2];
#pragma unroll
        for (int ks = 0; ks < 2; ++ks)
#pragma unroll
            for (int dt = 0; dt < 2; ++dt)
                bv[ks][dt] = *(const bf16x8*)(vw + (dt * 16 + c) * 128 +
                              ((ks * 64 + q * 16) ^ ((c & 7) << 4)));

        // O = P V
        f32x4_t o[4][2];
#pragma unroll
        for (int i = 0; i < 4; ++i)
#pragma unroll
            for (int dt = 0; dt < 2; ++dt)
                o[i][dt] = (f32x4_t){0.f, 0.f, 0.f, 0.f};
#pragma unroll
        for (int ks = 0; ks < 2; ++ks)
#pragma unroll
            for (int i = 0; i < 4; ++i) {
                const int n = i * 16 + c;
                bf16x8 ap = *(const bf16x8*)((char*)pw + n * 128 +
                             ((ks * 64 + q * 16) ^ ((n & 7) << 4)));
#pragma unroll
                for (int dt = 0; dt < 2; ++dt)
                    o[i][dt] = __builtin_amdgcn_mfma_f32_16x16x32_bf16(ap, bv[ks][dt], o[i][dt], 0, 0, 0);
            }

        // normalize + store
        bf16* ob = obuf + rowb * 512 + head * 32;
#pragma unroll
        for (int i = 0; i < 4; ++i)
#pragma unroll
            for (int dt = 0; dt < 2; ++dt)
#pragma unroll
                for (int jj = 0; jj < 4; ++jj) {
                    const int n = i * 16 + q * 4 + jj;
                    ob[(size_t)n * 512 + dt * 16 + c] = (bf16)(o[i][dt][jj] * inv[i][jj]);
                }
    }
}

// ---------------- bf16 GEMM (R7-proven): C[M,N] = A[M,K] * Bw[N,K]^T + bias ----------------
// 128x128, BK=64, single LDS buffer, explicit vmcnt(0)+__syncthreads (RAW) +
// __syncthreads (WAR). T2 pre-swizzled source; T1 bijective XCD swizzle.
// MODE 0: +bias -> bf16 (QKV) | 1: +bias,gelu -> fp8 x64 (MLP1)
// MODE 2: +bias +x, ungroup -> f32 (proj)
template<int MODE, int NBX>
__global__ __launch_bounds__(256, 2)
void gemm_bt(const bf16* __restrict__ A, const bf16* __restrict__ Bw,
             const float* __restrict__ bias, const float* __restrict__ resid,
             bf16* __restrict__ outb, float* __restrict__ outf,
             int N, int K)
{
    __shared__ alignas(16) bf16 As[128 * 64];
    __shared__ alignas(16) bf16 Bs[128 * 64];
    const int tid = threadIdx.x;
    const int lane = tid & 63;
    const int w = tid >> 6;
    const int wr = w >> 1, wc = w & 1;

    const int bid = blockIdx.y * NBX + blockIdx.x;
    const int nwg = gridDim.y * NBX;
    const int swz = (bid & 7) * (nwg >> 3) + (bid >> 3);
    const int by = swz / NBX;
    const int bx = swz - by * NBX;
    const int rowBase = by * 128;
    const int colBase = bx * 128;

    f32x4_t acc[4][4];
#pragma unroll
    for (int m = 0; m < 4; ++m)
#pragma unroll
        for (int n = 0; n < 4; ++n)
            acc[m][n] = (f32x4_t){0.f, 0.f, 0.f, 0.f};

    const int sw = (lane & 7) << 4;  // read-side XOR: (row&7)<<4, row&7 == lane&7

    for (int kt = 0; kt < K; kt += 64) {
#pragma unroll
        for (int l = 0; l < 4; ++l) {
            const int cg = l * 256 + tid;
            const int row = cg >> 3;
            const int col8 = (cg & 7) ^ (row & 7);
            const int cu = l * 256 + (tid & 192);
            ASYNC_COPY16(A + (size_t)(rowBase + row) * K + kt + col8 * 8, As + cu * 8);
            ASYNC_COPY16(Bw + (size_t)(colBase + row) * K + kt + col8 * 8, Bs + cu * 8);
        }
        WAITV0();
        __syncthreads();
#pragma unroll
        for (int kk = 0; kk < 64; kk += 32) {
            const int bofs = kk * 2 + (lane >> 4) * 16;
            bf16x8 af[4], bfr[4];
#pragma unroll
            for (int m = 0; m < 4; ++m) {
                const int row = wr * 64 + m * 16 + (lane & 15);
                af[m] = *(const bf16x8*)((const char*)As + row * 128 + (bofs ^ sw));
            }
#pragma unroll
            for (int n = 0; n < 4; ++n) {
                const int row = wc * 64 + n * 16 + (lane & 15);
                bfr[n] = *(const bf16x8*)((const char*)Bs + row * 128 + (bofs ^ sw));
            }
#pragma unroll
            for (int m = 0; m < 4; ++m)
#pragma unroll
                for (int n = 0; n < 4; ++n)
                    acc[m][n] = __builtin_amdgcn_mfma_f32_16x16x32_bf16(af[m], bfr[n], acc[m][n], 0, 0, 0);
        }
        __syncthreads();
    }

#pragma unroll
    for (int m = 0; m < 4; ++m) {
#pragma unroll
        for (int jj = 0; jj < 4; ++jj) {
            int grow = rowBase + wr * 64 + m * 16 + (lane >> 4) * 4 + jj;
#pragma unroll
            for (int n = 0; n < 4; ++n) {
                int gcol = colBase + wc * 64 + n * 16 + (lane & 15);
                float v = acc[m][n][jj] + bias[gcol];
                if constexpr (MODE == 0) {
                    outb[(size_t)grow * N + gcol] = (bf16)v;
                } else if constexpr (MODE == 1) {
                    // gelu(v) ~= v * sigmoid(1.5957691*(v + 0.044715 v^3)); write fp8 x64
                    float e = __expf(1.5957691216057308f * (v + 0.044715f * v * v * v));
                    v = v * (e / (1.0f + e));
                    int p8 = __builtin_amdgcn_cvt_pk_fp8_f32(v * 64.0f, v * 64.0f, 0, false);
                    ((unsigned char*)outb)[(size_t)grow * N + gcol] = (unsigned char)(p8 & 0xff);
                } else if constexpr (MODE == 2) {
                    int g = grow >> 6, ns = grow & 63;
                    int b = g >> 6, i = (g >> 3) & 7, j = g & 7;
                    int a = ns >> 3, u = ns & 7;
                    int t = b * 4096 + (a * 8 + i) * 64 + (u * 8 + j);
                    size_t oi = (size_t)t * 512 + gcol;
                    outf[oi] = resid[oi] + v;
                }
            }
        }
    }
}

// ---------------- fp8 GEMM (MLP2): C = A_fp8[M,K] * Bw_fp8[N,K]^T * invs + bias + resid ----------------
// 128x128, BK=64 fp8 (64B rows, 4x16B slots). Slot swizzle keyed on (row>>1)&3 (the
// R6-verified conflict-free variant); source pre-swizzled, LDS dest linear. Reads =
// ds_read_b64 at the bank floor. Sync = R7-proven vmcnt(0)+__syncthreads pair.
template<int NBX>
__global__ __launch_bounds__(256, 2)
void gemm_fp8(const unsigned char* __restrict__ A, const unsigned char* __restrict__ Bw,
              const float* __restrict__ bias, const float* __restrict__ resid,
              float* __restrict__ outf, int N, int K, float invs)
{
    __shared__ alignas(16) unsigned char As[128 * 64];  // 8 KiB
    __shared__ alignas(16) unsigned char Bs[128 * 64];  // 8 KiB
    const int tid = threadIdx.x;
    const int lane = tid & 63;
    const int w = tid >> 6;
    const int wr = w >> 1, wc = w & 1;
    const int c = lane & 15, q = lane >> 4;

    const int bid = blockIdx.y * NBX + blockIdx.x;
    const int nwg = gridDim.y * NBX;
    const int swz = (bid & 7) * (nwg >> 3) + (bid >> 3);
    const int by = swz / NBX;
    const int bx = swz - by * NBX;
    const int rowBase = by * 128;
    const int colBase = bx * 128;

    f32x4_t acc[4][4];
#pragma unroll
    for (int m = 0; m < 4; ++m)
#pragma unroll
        for (int n = 0; n < 4; ++n)
            acc[m][n] = (f32x4_t){0.f, 0.f, 0.f, 0.f};

    const int f = (c >> 1) & 3;          // (row>>1)&3 for rows ...*16 + c
    const int hb8 = (q & 1) * 8;

    for (int kt = 0; kt < K; kt += 64) {
        // stage: 2 chunks/thread each for A,B; chunk cg -> row=cg>>2, phys slot=cg&3;
        // source slot pre-swizzled: (cg&3) ^ ((row>>1)&3) = (cg&3)^((cg>>3)&3)
#pragma unroll
        for (int l = 0; l < 2; ++l) {
            const int cg = l * 256 + tid;
            const int row = cg >> 2;
            const int sg = (cg & 3) ^ ((cg >> 3) & 3);
            const int cu = l * 256 + (tid & 192);
            ASYNC_COPY16(A + (size_t)(rowBase + row) * K + kt + sg * 16, As + cu * 16);
            ASYNC_COPY16(Bw + (size_t)(colBase + row) * K + kt + sg * 16, Bs + cu * 16);
        }
        WAITV0();
        __syncthreads();
#pragma unroll
        for (int kk = 0; kk < 64; kk += 32) {
            const int sb = (((((kk >> 4) + (q >> 1)) ^ f) << 4)) + hb8;
            long af[4], bfr[4];
#pragma unroll
            for (int m = 0; m < 4; ++m) {
                const int row = wr * 64 + m * 16 + c;
                af[m] = *(const long*)((const char*)As + row * 64 + sb);
            }
#pragma unroll
            for (int n = 0; n < 4; ++n) {
                const int row = wc * 64 + n * 16 + c;
                bfr[n] = *(const long*)((const char*)Bs + row * 64 + sb);
            }
#pragma unroll
            for (int m = 0; m < 4; ++m)
#pragma unroll
                for (int n = 0; n < 4; ++n)
                    acc[m][n] = __builtin_amdgcn_mfma_f32_16x16x32_fp8_fp8(af[m], bfr[n], acc[m][n], 0, 0, 0);
        }
        __syncthreads();
    }

#pragma unroll
    for (int m = 0; m < 4; ++m) {
#pragma unroll
        for (int jj = 0; jj < 4; ++jj) {
            int grow = rowBase + wr * 64 + m * 16 + q * 4 + jj;
#pragma unroll
            for (int n = 0; n < 4; ++n) {
                int gcol = colBase + wc * 64 + n * 16 + c;
                float v = acc[m][n][jj] * invs + bias[gcol];
                size_t oi = (size_t)grow * 512 + gcol;
                outf[oi] = resid[oi] + v;
            }
        }
    }
}

// ---------------- launcher ----------------
extern "C" void kernel_launch(void* const* d_in, const int* in_sizes, int n_in,
                              void* d_out, int out_size, void* d_ws, size_t ws_size,
                              hipStream_t stream)
{
    const float* x    = (const float*)d_in[0];
    const float* n1g  = (const float*)d_in[1];
    const float* n1b  = (const float*)d_in[2];
    const float* qkvw = (const float*)d_in[3];
    const float* qkvb = (const float*)d_in[4];
    const float* pjw  = (const float*)d_in[5];
    const float* pjb  = (const float*)d_in[6];
    const float* pw0  = (const float*)d_in[7];
    const float* pb0  = (const float*)d_in[8];
    const float* pg0  = (const float*)d_in[9];
    const float* pbb0 = (const float*)d_in[10];
    const float* pw1  = (const float*)d_in[11];
    const float* pb1  = (const float*)d_in[12];
    const float* pg1  = (const float*)d_in[13];
    const float* pbb1 = (const float*)d_in[14];
    const float* pw2  = (const float*)d_in[15];
    const float* pb2  = (const float*)d_in[16];
    const float* pg2  = (const float*)d_in[17];
    const float* pbb2 = (const float*)d_in[18];
    const float* pw3  = (const float*)d_in[19];
    const float* pb3  = (const float*)d_in[20];
    const float* n2g  = (const float*)d_in[21];
    const float* n2b  = (const float*)d_in[22];
    const float* w1   = (const float*)d_in[23];
    const float* b1   = (const float*)d_in[24];
    const float* w2   = (const float*)d_in[25];
    const float* b2   = (const float*)d_in[26];

    char* ws = (char*)d_ws;
    bf16* qkvw_b = (bf16*)(ws + OFF_QKVW);
    bf16* pjw_b  = (bf16*)(ws + OFF_PROJW);
    bf16* w1_b   = (bf16*)(ws + OFF_W1);
    unsigned char* w2_f8 = (unsigned char*)(ws + OFF_W2);
    float* ptab  = (float*)(ws + OFF_PTAB);
    bf16* bufA   = (bf16*)(ws + OFF_A);
    bf16* bufB   = (bf16*)(ws + OFF_B);
    float* xout  = (float*)d_out;

    // weight casts
    cast_bf16_k<<<(1536 * 512 / 4 + 255) / 256, 256, 0, stream>>>(qkvw, qkvw_b, 1536 * 512 / 4);
    cast_bf16_k<<<(512 * 512 / 4 + 255) / 256, 256, 0, stream>>>(pjw, pjw_b, 512 * 512 / 4);
    cast_bf16_k<<<(2048 * 512 / 4 + 255) / 256, 256, 0, stream>>>(w1, w1_b, 2048 * 512 / 4);
    cast_fp8_k<<<(512 * 2048 / 4 + 255) / 256, 256, 0, stream>>>(w2, w2_f8, 512 * 2048 / 4);

    // pos-bias table
    posmlp_k<<<1, 256, 0, stream>>>(pw0, pb0, pg0, pbb0, pw1, pb1, pg1, pbb1,
                                    pw2, pb2, pg2, pbb2, pw3, pb3, ptab);

    // LN1 + group -> bufB
    ln_k<1><<<16384, 256, 0, stream>>>(x, n1g, n1b, bufB);

    // QKV -> bufA
    gemm_bt<0, 12><<<dim3(12, 512), 256, 0, stream>>>(bufB, qkvw_b, qkvb, nullptr, bufA, nullptr, 1536, 512);

    // attention -> bufB
    attn_mfma_k<<<2048, 256, 0, stream>>>(bufA, ptab, bufB);

    // proj + ungroup + residual(x) -> d_out (x1)
    gemm_bt<2, 4><<<dim3(4, 512), 256, 0, stream>>>(bufB, pjw_b, pjb, x, nullptr, xout, 512, 512);

    // LN2 -> bufB
    ln_k<0><<<16384, 256, 0, stream>>>(xout, n2g, n2b, bufB);

    // MLP1 + gelu -> bufA as fp8 x64
    gemm_bt<1, 16><<<dim3(16, 512), 256, 0, stream>>>(bufB, w1_b, b1, nullptr, bufA, nullptr, 2048, 512);

    // MLP2 (fp8) + residual(x1) -> d_out (in place); invs = 1/(64*64)
    gemm_fp8<4><<<dim3(4, 512), 256, 0, stream>>>((const unsigned char*)bufA, w2_f8, b2,
                                                  xout, xout, 512, 2048, 1.0f / 4096.0f);
}

// Round 13
// 736.052 us; speedup vs baseline: 1.2827x; 1.1069x over previous
//
#include <hip/hip_runtime.h>
#include <hip/hip_bf16.h>

typedef __bf16 bf16;
typedef __bf16 bf16x8 __attribute__((ext_vector_type(8)));
typedef __bf16 bf16x4 __attribute__((ext_vector_type(4)));
typedef float f32x4_t __attribute__((ext_vector_type(4)));

static constexpr int kDIM = 512;

// ---------------- ws layout (bytes) ----------------
static constexpr size_t OFF_QKVW = 0;                         // 1536*512 fp8
static constexpr size_t OFF_PROJW = 1572864;                  // 512*512 bf16
static constexpr size_t OFF_W1   = 2097152;                   // 2048*512 fp8
static constexpr size_t OFF_W2   = 4194304;                   // 512*2048 fp8
static constexpr size_t OFF_PTAB = 6291456;                   // 225*16 f32
static constexpr size_t OFF_A    = 8388608;                   // qkv bf16 / hidden fp8
static constexpr size_t OFF_B    = 276824064;                 // ln fp8 / o bf16

typedef __attribute__((address_space(3))) uint32_t lds_u32_t;
typedef __attribute__((address_space(1))) const uint32_t glb_u32_t;
#define ASYNC_COPY16(gp, lp) __builtin_amdgcn_global_load_lds((glb_u32_t*)(gp), (lds_u32_t*)(lp), 16, 0, 0)
#define WAITV0() asm volatile("s_waitcnt vmcnt(0)" ::: "memory")

// ---------------- fp32 -> bf16 cast ----------------
__global__ void cast_bf16_k(const float* __restrict__ in, bf16* __restrict__ out, int n4)
{
    int i = blockIdx.x * blockDim.x + threadIdx.x;
    if (i < n4) {
        float4 v = ((const float4*)in)[i];
        bf16x4 o; o[0] = (bf16)v.x; o[1] = (bf16)v.y; o[2] = (bf16)v.z; o[3] = (bf16)v.w;
        ((bf16x4*)out)[i] = o;
    }
}

// ---------------- fp32 -> fp8 e4m3 cast with x64 scale ----------------
__global__ void cast_fp8_k(const float* __restrict__ in, unsigned char* __restrict__ out, int n4)
{
    int i = blockIdx.x * blockDim.x + threadIdx.x;
    if (i < n4) {
        float4 v = ((const float4*)in)[i];
        int p = __builtin_amdgcn_cvt_pk_fp8_f32(v.x * 64.0f, v.y * 64.0f, 0, false);
        p = __builtin_amdgcn_cvt_pk_fp8_f32(v.z * 64.0f, v.w * 64.0f, p, true);
        ((unsigned int*)out)[i] = (unsigned int)p;
    }
}

// ---------------- LayerNorm (+ optional LDA grouping) -> fp8 x32 ----------------
template<int GROUP>
__global__ __launch_bounds__(256)
void ln_k(const float* __restrict__ x, const float* __restrict__ gw,
          const float* __restrict__ bw, unsigned char* __restrict__ out)
{
    const int t = blockIdx.x * 4 + (threadIdx.x >> 6);
    const int lane = threadIdx.x & 63;
    const float* xp = x + (size_t)t * kDIM + lane * 8;
    float4 p0 = *(const float4*)xp;
    float4 p1 = *(const float4*)(xp + 4);
    float v[8] = {p0.x, p0.y, p0.z, p0.w, p1.x, p1.y, p1.z, p1.w};
    float s = 0.f;
#pragma unroll
    for (int i = 0; i < 8; ++i) s += v[i];
#pragma unroll
    for (int off = 32; off > 0; off >>= 1) s += __shfl_xor(s, off);
    const float mean = s * (1.0f / 512.0f);
    float q = 0.f;
#pragma unroll
    for (int i = 0; i < 8; ++i) { float d = v[i] - mean; q += d * d; }
#pragma unroll
    for (int off = 32; off > 0; off >>= 1) q += __shfl_xor(q, off);
    const float rstd = rsqrtf(q * (1.0f / 512.0f) + 1e-5f);
    size_t orow;
    if (GROUP) {
        int b = t >> 12, r = (t >> 6) & 63, c = t & 63;
        int g = b * 64 + (r & 7) * 8 + (c & 7);
        int n = (r >> 3) * 8 + (c >> 3);
        orow = (size_t)g * 64 + n;
    } else {
        orow = t;
    }
    float4 g0 = *(const float4*)(gw + lane * 8);
    float4 g1 = *(const float4*)(gw + lane * 8 + 4);
    float4 b0 = *(const float4*)(bw + lane * 8);
    float4 b1 = *(const float4*)(bw + lane * 8 + 4);
    float gg[8] = {g0.x, g0.y, g0.z, g0.w, g1.x, g1.y, g1.z, g1.w};
    float bb[8] = {b0.x, b0.y, b0.z, b0.w, b1.x, b1.y, b1.z, b1.w};
    float o[8];
#pragma unroll
    for (int i = 0; i < 8; ++i) o[i] = ((v[i] - mean) * rstd * gg[i] + bb[i]) * 32.0f;
    unsigned int lo = 0, hi = 0;
    lo = (unsigned int)__builtin_amdgcn_cvt_pk_fp8_f32(o[0], o[1], 0, false);
    lo = (unsigned int)__builtin_amdgcn_cvt_pk_fp8_f32(o[2], o[3], (int)lo, true);
    hi = (unsigned int)__builtin_amdgcn_cvt_pk_fp8_f32(o[4], o[5], 0, false);
    hi = (unsigned int)__builtin_amdgcn_cvt_pk_fp8_f32(o[6], o[7], (int)hi, true);
    uint2 u; u.x = lo; u.y = hi;
    *(uint2*)(out + orow * kDIM + lane * 8) = u;
}

// ---------------- dynamic position bias MLP: 225 rows, 2->32->32->32->16 ----------------
__device__ inline void ln32_relu(float* h, const float* g, const float* b)
{
    float m = 0.f;
#pragma unroll
    for (int i = 0; i < 32; ++i) m += h[i];
    m *= (1.0f / 32.0f);
    float v = 0.f;
#pragma unroll
    for (int i = 0; i < 32; ++i) { float d = h[i] - m; v += d * d; }
    v *= (1.0f / 32.0f);
    float r = rsqrtf(v + 1e-5f);
#pragma unroll
    for (int i = 0; i < 32; ++i) h[i] = fmaxf((h[i] - m) * r * g[i] + b[i], 0.f);
}

__global__ __launch_bounds__(256)
void posmlp_k(const float* __restrict__ w0, const float* __restrict__ b0,
              const float* __restrict__ g0, const float* __restrict__ bb0,
              const float* __restrict__ w1, const float* __restrict__ b1,
              const float* __restrict__ g1, const float* __restrict__ bb1,
              const float* __restrict__ w2, const float* __restrict__ b2,
              const float* __restrict__ g2, const float* __restrict__ bb2,
              const float* __restrict__ w3, const float* __restrict__ b3,
              float* __restrict__ ptab)
{
    int r = threadIdx.x;
    if (r >= 225) return;
    float in0 = (float)(r / 15) - 7.0f;
    float in1 = (float)(r % 15) - 7.0f;
    float h[32], h2[32];
#pragma unroll
    for (int o = 0; o < 32; ++o) h[o] = w0[o * 2] * in0 + w0[o * 2 + 1] * in1 + b0[o];
    ln32_relu(h, g0, bb0);
#pragma unroll
    for (int o = 0; o < 32; ++o) {
        float s = b1[o];
#pragma unroll
        for (int i = 0; i < 32; ++i) s += w1[o * 32 + i] * h[i];
        h2[o] = s;
    }
    ln32_relu(h2, g1, bb1);
#pragma unroll
    for (int o = 0; o < 32; ++o) {
        float s = b2[o];
#pragma unroll
        for (int i = 0; i < 32; ++i) s += w2[o * 32 + i] * h2[i];
        h[o] = s;
    }
    ln32_relu(h, g2, bb2);
#pragma unroll
    for (int o = 0; o < 16; ++o) {
        float s = b3[o];
#pragma unroll
        for (int i = 0; i < 32; ++i) s += w3[o * 32 + i] * h[i];
        ptab[r * 16 + o] = s;
    }
}

// ---------------- attention via MFMA: block = (group, head-octet), 4 waves x 2 heads ----------------
__global__ __launch_bounds__(256)
void attn_mfma_k(const bf16* __restrict__ qkv, const float* __restrict__ ptab,
                 bf16* __restrict__ obuf)
{
    const int g  = blockIdx.x >> 1;
    const int hb = blockIdx.x & 1;
    const int w  = threadIdx.x >> 6;
    const int lane = threadIdx.x & 63;
    const int c = lane & 15, q = lane >> 4;

    __shared__ float ptl[16][240];                 // ptab transposed [head][idx]
    __shared__ alignas(16) bf16 pl[4][4096];       // per-wave P (64x64), XOR-swizzled
    __shared__ alignas(16) bf16 vt[4][2048];       // per-wave V^T (32 d x 64 m), swizzled

    for (int i = threadIdx.x; i < 3600; i += 256)
        ptl[i & 15][i >> 4] = ptab[i];
    __syncthreads();

    const size_t rowb = (size_t)g * 64;
    bf16* pw = pl[w];
    char* vw = (char*)vt[w];

    for (int hh = 0; hh < 2; ++hh) {
        const int head = hb * 8 + hh * 4 + w;
        const bf16* qb = qkv + rowb * 1536 + head * 32;

        // V rows: coalesced 16B loads (issued first; land under QK^T)
        bf16x8 vrow[4];
#pragma unroll
        for (int l = 0; l < 4; ++l)
            vrow[l] = *(const bf16x8*)(qb + 1024 + (size_t)lane * 1536 + l * 8);

        // Q A-frags, K B-frags (16B/lane)
        bf16x8 aq[4], bk[4];
#pragma unroll
        for (int i = 0; i < 4; ++i) {
            aq[i] = *(const bf16x8*)(qb + (size_t)(i * 16 + c) * 1536 + q * 8);
            bk[i] = *(const bf16x8*)(qb + 512 + (size_t)(i * 16 + c) * 1536 + q * 8);
        }

        // S = Q K^T
        f32x4_t s[4][4];
#pragma unroll
        for (int i = 0; i < 4; ++i)
#pragma unroll
            for (int j = 0; j < 4; ++j)
                s[i][j] = __builtin_amdgcn_mfma_f32_16x16x32_bf16(aq[i], bk[j],
                          (f32x4_t){0.f, 0.f, 0.f, 0.f}, 0, 0, 0);

        // V^T -> LDS (row d, offset m*2 XOR (d&7)<<4)
#pragma unroll
        for (int l = 0; l < 4; ++l)
#pragma unroll
            for (int j = 0; j < 8; ++j) {
                const int d = l * 8 + j;
                *(bf16*)(vw + d * 128 + ((lane * 2) ^ ((d & 7) << 4))) = vrow[l][j];
            }

        // scale + rel-pos bias + row softmax
        const float scale = 0.17677669529663687f;  // 1/sqrt(32)
        float inv[4][4];
#pragma unroll
        for (int i = 0; i < 4; ++i)
#pragma unroll
            for (int jj = 0; jj < 4; ++jj) {
                const int n = i * 16 + q * 4 + jj;
                const int na = n >> 3, nu = n & 7;
                float mx = -1e30f;
#pragma unroll
                for (int j = 0; j < 4; ++j) {
                    const int m = j * 16 + c;
                    const int idx = (na - (m >> 3) + 7) * 15 + (nu - (m & 7) + 7);
                    float v = s[i][j][jj] * scale + ptl[head][idx];
                    s[i][j][jj] = v;
                    mx = fmaxf(mx, v);
                }
#pragma unroll
                for (int off = 1; off < 16; off <<= 1) mx = fmaxf(mx, __shfl_xor(mx, off));
                float sum = 0.f;
#pragma unroll
                for (int j = 0; j < 4; ++j) {
                    float e = __expf(s[i][j][jj] - mx);
                    s[i][j][jj] = e; sum += e;
                }
#pragma unroll
                for (int off = 1; off < 16; off <<= 1) sum += __shfl_xor(sum, off);
                inv[i][jj] = 1.0f / sum;
            }

        // P -> LDS (bf16, swizzled: byte ^= (row&7)<<4)
#pragma unroll
        for (int i = 0; i < 4; ++i)
#pragma unroll
            for (int jj = 0; jj < 4; ++jj) {
                const int n = i * 16 + q * 4 + jj;
                const int swz = (n & 7) << 4;
#pragma unroll
                for (int j = 0; j < 4; ++j) {
                    const int m = j * 16 + c;
                    *(bf16*)((char*)pw + n * 128 + ((m * 2) ^ swz)) = (bf16)s[i][j][jj];
                }
            }

        // V B-frags from LDS V^T
        bf16x8 bv[2][2];
#pragma unroll
        for (int ks = 0; ks < 2; ++ks)
#pragma unroll
            for (int dt = 0; dt < 2; ++dt)
                bv[ks][dt] = *(const bf16x8*)(vw + (dt * 16 + c) * 128 +
                              ((ks * 64 + q * 16) ^ ((c & 7) << 4)));

        // O = P V
        f32x4_t o[4][2];
#pragma unroll
        for (int i = 0; i < 4; ++i)
#pragma unroll
            for (int dt = 0; dt < 2; ++dt)
                o[i][dt] = (f32x4_t){0.f, 0.f, 0.f, 0.f};
#pragma unroll
        for (int ks = 0; ks < 2; ++ks)
#pragma unroll
            for (int i = 0; i < 4; ++i) {
                const int n = i * 16 + c;
                bf16x8 ap = *(const bf16x8*)((char*)pw + n * 128 +
                             ((ks * 64 + q * 16) ^ ((n & 7) << 4)));
#pragma unroll
                for (int dt = 0; dt < 2; ++dt)
                    o[i][dt] = __builtin_amdgcn_mfma_f32_16x16x32_bf16(ap, bv[ks][dt], o[i][dt], 0, 0, 0);
            }

        // normalize + store
        bf16* ob = obuf + rowb * 512 + head * 32;
#pragma unroll
        for (int i = 0; i < 4; ++i)
#pragma unroll
            for (int dt = 0; dt < 2; ++dt)
#pragma unroll
                for (int jj = 0; jj < 4; ++jj) {
                    const int n = i * 16 + q * 4 + jj;
                    ob[(size_t)n * 512 + dt * 16 + c] = (bf16)(o[i][dt][jj] * inv[i][jj]);
                }
    }
}

// ---------------- bf16 GEMM (R7-proven), proj only ----------------
// MODE 2: +bias +x, ungroup -> f32 (proj)
template<int MODE, int NBX>
__global__ __launch_bounds__(256, 2)
void gemm_bt(const bf16* __restrict__ A, const bf16* __restrict__ Bw,
             const float* __restrict__ bias, const float* __restrict__ resid,
             bf16* __restrict__ outb, float* __restrict__ outf,
             int N, int K)
{
    __shared__ alignas(16) bf16 As[128 * 64];
    __shared__ alignas(16) bf16 Bs[128 * 64];
    const int tid = threadIdx.x;
    const int lane = tid & 63;
    const int w = tid >> 6;
    const int wr = w >> 1, wc = w & 1;

    const int bid = blockIdx.y * NBX + blockIdx.x;
    const int nwg = gridDim.y * NBX;
    const int swz = (bid & 7) * (nwg >> 3) + (bid >> 3);
    const int by = swz / NBX;
    const int bx = swz - by * NBX;
    const int rowBase = by * 128;
    const int colBase = bx * 128;

    f32x4_t acc[4][4];
#pragma unroll
    for (int m = 0; m < 4; ++m)
#pragma unroll
        for (int n = 0; n < 4; ++n)
            acc[m][n] = (f32x4_t){0.f, 0.f, 0.f, 0.f};

    const int sw = (lane & 7) << 4;

    for (int kt = 0; kt < K; kt += 64) {
#pragma unroll
        for (int l = 0; l < 4; ++l) {
            const int cg = l * 256 + tid;
            const int row = cg >> 3;
            const int col8 = (cg & 7) ^ (row & 7);
            const int cu = l * 256 + (tid & 192);
            ASYNC_COPY16(A + (size_t)(rowBase + row) * K + kt + col8 * 8, As + cu * 8);
            ASYNC_COPY16(Bw + (size_t)(colBase + row) * K + kt + col8 * 8, Bs + cu * 8);
        }
        WAITV0();
        __syncthreads();
#pragma unroll
        for (int kk = 0; kk < 64; kk += 32) {
            const int bofs = kk * 2 + (lane >> 4) * 16;
            bf16x8 af[4], bfr[4];
#pragma unroll
            for (int m = 0; m < 4; ++m) {
                const int row = wr * 64 + m * 16 + (lane & 15);
                af[m] = *(const bf16x8*)((const char*)As + row * 128 + (bofs ^ sw));
            }
#pragma unroll
            for (int n = 0; n < 4; ++n) {
                const int row = wc * 64 + n * 16 + (lane & 15);
                bfr[n] = *(const bf16x8*)((const char*)Bs + row * 128 + (bofs ^ sw));
            }
#pragma unroll
            for (int m = 0; m < 4; ++m)
#pragma unroll
                for (int n = 0; n < 4; ++n)
                    acc[m][n] = __builtin_amdgcn_mfma_f32_16x16x32_bf16(af[m], bfr[n], acc[m][n], 0, 0, 0);
        }
        __syncthreads();
    }

#pragma unroll
    for (int m = 0; m < 4; ++m) {
#pragma unroll
        for (int jj = 0; jj < 4; ++jj) {
            int grow = rowBase + wr * 64 + m * 16 + (lane >> 4) * 4 + jj;
#pragma unroll
            for (int n = 0; n < 4; ++n) {
                int gcol = colBase + wc * 64 + n * 16 + (lane & 15);
                float v = acc[m][n][jj] + bias[gcol];
                if constexpr (MODE == 0) {
                    outb[(size_t)grow * N + gcol] = (bf16)v;
                } else if constexpr (MODE == 2) {
                    int g = grow >> 6, ns = grow & 63;
                    int b = g >> 6, i = (g >> 3) & 7, j = g & 7;
                    int a = ns >> 3, u = ns & 7;
                    int t = b * 4096 + (a * 8 + i) * 64 + (u * 8 + j);
                    size_t oi = (size_t)t * 512 + gcol;
                    outf[oi] = resid[oi] + v;
                }
            }
        }
    }
}

// ---------------- fp8 GEMM: C = A_fp8[M,K] * Bw_fp8[N,K]^T * invs + bias, epilogues ----------------
// 128x128, BK=64 fp8 (64B rows, 4x16B slots), slot swizzle keyed (row>>1)&3 (R12-verified).
// MODE 0: -> bf16 (QKV) | 1: gelu -> fp8 x64 (MLP1) | 3: +resid -> f32 (MLP2)
template<int MODE, int NBX>
__global__ __launch_bounds__(256, 2)
void gemm_fp8(const unsigned char* __restrict__ A, const unsigned char* __restrict__ Bw,
              const float* __restrict__ bias, const float* __restrict__ resid,
              void* __restrict__ outp, int N, int K, float invs)
{
    __shared__ alignas(16) unsigned char As[128 * 64];  // 8 KiB
    __shared__ alignas(16) unsigned char Bs[128 * 64];  // 8 KiB
    const int tid = threadIdx.x;
    const int lane = tid & 63;
    const int w = tid >> 6;
    const int wr = w >> 1, wc = w & 1;
    const int c = lane & 15, q = lane >> 4;

    const int bid = blockIdx.y * NBX + blockIdx.x;
    const int nwg = gridDim.y * NBX;
    const int swz = (bid & 7) * (nwg >> 3) + (bid >> 3);
    const int by = swz / NBX;
    const int bx = swz - by * NBX;
    const int rowBase = by * 128;
    const int colBase = bx * 128;

    f32x4_t acc[4][4];
#pragma unroll
    for (int m = 0; m < 4; ++m)
#pragma unroll
        for (int n = 0; n < 4; ++n)
            acc[m][n] = (f32x4_t){0.f, 0.f, 0.f, 0.f};

    const int f = (c >> 1) & 3;          // (row>>1)&3 for rows ...*16 + c
    const int hb8 = (q & 1) * 8;

    for (int kt = 0; kt < K; kt += 64) {
#pragma unroll
        for (int l = 0; l < 2; ++l) {
            const int cg = l * 256 + tid;
            const int row = cg >> 2;
            const int sg = (cg & 3) ^ ((cg >> 3) & 3);
            const int cu = l * 256 + (tid & 192);
            ASYNC_COPY16(A + (size_t)(rowBase + row) * K + kt + sg * 16, As + cu * 16);
            ASYNC_COPY16(Bw + (size_t)(colBase + row) * K + kt + sg * 16, Bs + cu * 16);
        }
        WAITV0();
        __syncthreads();
#pragma unroll
        for (int kk = 0; kk < 64; kk += 32) {
            const int sb = (((((kk >> 4) + (q >> 1)) ^ f) << 4)) + hb8;
            long af[4], bfr[4];
#pragma unroll
            for (int m = 0; m < 4; ++m) {
                const int row = wr * 64 + m * 16 + c;
                af[m] = *(const long*)((const char*)As + row * 64 + sb);
            }
#pragma unroll
            for (int n = 0; n < 4; ++n) {
                const int row = wc * 64 + n * 16 + c;
                bfr[n] = *(const long*)((const char*)Bs + row * 64 + sb);
            }
#pragma unroll
            for (int m = 0; m < 4; ++m)
#pragma unroll
                for (int n = 0; n < 4; ++n)
                    acc[m][n] = __builtin_amdgcn_mfma_f32_16x16x32_fp8_fp8(af[m], bfr[n], acc[m][n], 0, 0, 0);
        }
        __syncthreads();
    }

#pragma unroll
    for (int m = 0; m < 4; ++m) {
#pragma unroll
        for (int jj = 0; jj < 4; ++jj) {
            int grow = rowBase + wr * 64 + m * 16 + q * 4 + jj;
#pragma unroll
            for (int n = 0; n < 4; ++n) {
                int gcol = colBase + wc * 64 + n * 16 + c;
                float v = acc[m][n][jj] * invs + bias[gcol];
                if constexpr (MODE == 0) {
                    ((bf16*)outp)[(size_t)grow * N + gcol] = (bf16)v;
                } else if constexpr (MODE == 1) {
                    // gelu(v) ~= v * sigmoid(1.5957691*(v + 0.044715 v^3)); write fp8 x64
                    float e = __expf(1.5957691216057308f * (v + 0.044715f * v * v * v));
                    v = v * (e / (1.0f + e));
                    int p8 = __builtin_amdgcn_cvt_pk_fp8_f32(v * 64.0f, v * 64.0f, 0, false);
                    ((unsigned char*)outp)[(size_t)grow * N + gcol] = (unsigned char)(p8 & 0xff);
                } else {
                    size_t oi = (size_t)grow * 512 + gcol;
                    ((float*)outp)[oi] = resid[oi] + v;
                }
            }
        }
    }
}

// ---------------- launcher ----------------
extern "C" void kernel_launch(void* const* d_in, const int* in_sizes, int n_in,
                              void* d_out, int out_size, void* d_ws, size_t ws_size,
                              hipStream_t stream)
{
    const float* x    = (const float*)d_in[0];
    const float* n1g  = (const float*)d_in[1];
    const float* n1b  = (const float*)d_in[2];
    const float* qkvw = (const float*)d_in[3];
    const float* qkvb = (const float*)d_in[4];
    const float* pjw  = (const float*)d_in[5];
    const float* pjb  = (const float*)d_in[6];
    const float* pw0  = (const float*)d_in[7];
    const float* pb0  = (const float*)d_in[8];
    const float* pg0  = (const float*)d_in[9];
    const float* pbb0 = (const float*)d_in[10];
    const float* pw1  = (const float*)d_in[11];
    const float* pb1  = (const float*)d_in[12];
    const float* pg1  = (const float*)d_in[13];
    const float* pbb1 = (const float*)d_in[14];
    const float* pw2  = (const float*)d_in[15];
    const float* pb2  = (const float*)d_in[16];
    const float* pg2  = (const float*)d_in[17];
    const float* pbb2 = (const float*)d_in[18];
    const float* pw3  = (const float*)d_in[19];
    const float* pb3  = (const float*)d_in[20];
    const float* n2g  = (const float*)d_in[21];
    const float* n2b  = (const float*)d_in[22];
    const float* w1   = (const float*)d_in[23];
    const float* b1   = (const float*)d_in[24];
    const float* w2   = (const float*)d_in[25];
    const float* b2   = (const float*)d_in[26];

    char* ws = (char*)d_ws;
    unsigned char* qkvw_f8 = (unsigned char*)(ws + OFF_QKVW);
    bf16* pjw_b  = (bf16*)(ws + OFF_PROJW);
    unsigned char* w1_f8 = (unsigned char*)(ws + OFF_W1);
    unsigned char* w2_f8 = (unsigned char*)(ws + OFF_W2);
    float* ptab  = (float*)(ws + OFF_PTAB);
    bf16* bufA   = (bf16*)(ws + OFF_A);          // qkv bf16 / hidden fp8
    unsigned char* bufA8 = (unsigned char*)(ws + OFF_A);
    unsigned char* bufB8 = (unsigned char*)(ws + OFF_B);  // LN outs fp8
    bf16* bufBb  = (bf16*)(ws + OFF_B);                    // attention out bf16
    float* xout  = (float*)d_out;

    // weight casts
    cast_fp8_k<<<(1536 * 512 / 4 + 255) / 256, 256, 0, stream>>>(qkvw, qkvw_f8, 1536 * 512 / 4);
    cast_bf16_k<<<(512 * 512 / 4 + 255) / 256, 256, 0, stream>>>(pjw, pjw_b, 512 * 512 / 4);
    cast_fp8_k<<<(2048 * 512 / 4 + 255) / 256, 256, 0, stream>>>(w1, w1_f8, 2048 * 512 / 4);
    cast_fp8_k<<<(512 * 2048 / 4 + 255) / 256, 256, 0, stream>>>(w2, w2_f8, 512 * 2048 / 4);

    // pos-bias table
    posmlp_k<<<1, 256, 0, stream>>>(pw0, pb0, pg0, pbb0, pw1, pb1, pg1, pbb1,
                                    pw2, pb2, pg2, pbb2, pw3, pb3, ptab);

    // LN1 + group -> bufB (fp8 x32)
    ln_k<1><<<16384, 256, 0, stream>>>(x, n1g, n1b, bufB8);

    // QKV (fp8) -> bufA bf16; invs = 1/(32*64)
    gemm_fp8<0, 12><<<dim3(12, 512), 256, 0, stream>>>(bufB8, qkvw_f8, qkvb, nullptr,
                                                       bufA, 1536, 512, 1.0f / 2048.0f);

    // attention -> bufB (bf16)
    attn_mfma_k<<<2048, 256, 0, stream>>>(bufA, ptab, bufBb);

    // proj (bf16) + ungroup + residual(x) -> d_out (x1)
    gemm_bt<2, 4><<<dim3(4, 512), 256, 0, stream>>>(bufBb, pjw_b, pjb, x, nullptr, xout, 512, 512);

    // LN2 -> bufB (fp8 x32)
    ln_k<0><<<16384, 256, 0, stream>>>(xout, n2g, n2b, bufB8);

    // MLP1 (fp8) + gelu -> bufA as fp8 x64; invs = 1/(32*64)
    gemm_fp8<1, 16><<<dim3(16, 512), 256, 0, stream>>>(bufB8, w1_f8, b1, nullptr,
                                                       bufA8, 2048, 512, 1.0f / 2048.0f);

    // MLP2 (fp8) + residual(x1) -> d_out (in place); invs = 1/(64*64)
    gemm_fp8<3, 4><<<dim3(4, 512), 256, 0, stream>>>(bufA8, w2_f8, b2, xout,
                                                     xout, 512, 2048, 1.0f / 4096.0f);
}

// Round 14
// 723.541 us; speedup vs baseline: 1.3049x; 1.0173x over previous
//
#include <hip/hip_runtime.h>
#include <hip/hip_bf16.h>

typedef __bf16 bf16;
typedef __bf16 bf16x8 __attribute__((ext_vector_type(8)));
typedef __bf16 bf16x4 __attribute__((ext_vector_type(4)));
typedef float f32x4_t __attribute__((ext_vector_type(4)));

static constexpr int kDIM = 512;

// ---------------- ws layout (bytes) ----------------
static constexpr size_t OFF_QKVW = 0;                         // 1536*512 fp8
static constexpr size_t OFF_PROJW = 1572864;                  // 512*512 fp8
static constexpr size_t OFF_W1   = 2097152;                   // 2048*512 fp8
static constexpr size_t OFF_W2   = 4194304;                   // 512*2048 fp8
static constexpr size_t OFF_PTAB = 6291456;                   // 225*16 f32
static constexpr size_t OFF_A    = 8388608;                   // qkv mixed (134MB) / hidden fp8
static constexpr size_t OFF_B    = 276824064;                 // ln fp8 / attn-out fp8

typedef __attribute__((address_space(3))) uint32_t lds_u32_t;
typedef __attribute__((address_space(1))) const uint32_t glb_u32_t;
#define ASYNC_COPY16(gp, lp) __builtin_amdgcn_global_load_lds((glb_u32_t*)(gp), (lds_u32_t*)(lp), 16, 0, 0)
#define WAITV0() asm volatile("s_waitcnt vmcnt(0)" ::: "memory")

// ---------------- fp32 -> fp8 e4m3 cast with x64 scale ----------------
__global__ void cast_fp8_k(const float* __restrict__ in, unsigned char* __restrict__ out, int n4)
{
    int i = blockIdx.x * blockDim.x + threadIdx.x;
    if (i < n4) {
        float4 v = ((const float4*)in)[i];
        int p = __builtin_amdgcn_cvt_pk_fp8_f32(v.x * 64.0f, v.y * 64.0f, 0, false);
        p = __builtin_amdgcn_cvt_pk_fp8_f32(v.z * 64.0f, v.w * 64.0f, p, true);
        ((unsigned int*)out)[i] = (unsigned int)p;
    }
}

// ---------------- LayerNorm (+ optional LDA grouping) -> fp8 x32 ----------------
template<int GROUP>
__global__ __launch_bounds__(256)
void ln_k(const float* __restrict__ x, const float* __restrict__ gw,
          const float* __restrict__ bw, unsigned char* __restrict__ out)
{
    const int t = blockIdx.x * 4 + (threadIdx.x >> 6);
    const int lane = threadIdx.x & 63;
    const float* xp = x + (size_t)t * kDIM + lane * 8;
    float4 p0 = *(const float4*)xp;
    float4 p1 = *(const float4*)(xp + 4);
    float v[8] = {p0.x, p0.y, p0.z, p0.w, p1.x, p1.y, p1.z, p1.w};
    float s = 0.f;
#pragma unroll
    for (int i = 0; i < 8; ++i) s += v[i];
#pragma unroll
    for (int off = 32; off > 0; off >>= 1) s += __shfl_xor(s, off);
    const float mean = s * (1.0f / 512.0f);
    float q = 0.f;
#pragma unroll
    for (int i = 0; i < 8; ++i) { float d = v[i] - mean; q += d * d; }
#pragma unroll
    for (int off = 32; off > 0; off >>= 1) q += __shfl_xor(q, off);
    const float rstd = rsqrtf(q * (1.0f / 512.0f) + 1e-5f);
    size_t orow;
    if (GROUP) {
        int b = t >> 12, r = (t >> 6) & 63, c = t & 63;
        int g = b * 64 + (r & 7) * 8 + (c & 7);
        int n = (r >> 3) * 8 + (c >> 3);
        orow = (size_t)g * 64 + n;
    } else {
        orow = t;
    }
    float4 g0 = *(const float4*)(gw + lane * 8);
    float4 g1 = *(const float4*)(gw + lane * 8 + 4);
    float4 b0 = *(const float4*)(bw + lane * 8);
    float4 b1 = *(const float4*)(bw + lane * 8 + 4);
    float gg[8] = {g0.x, g0.y, g0.z, g0.w, g1.x, g1.y, g1.z, g1.w};
    float bb[8] = {b0.x, b0.y, b0.z, b0.w, b1.x, b1.y, b1.z, b1.w};
    float o[8];
#pragma unroll
    for (int i = 0; i < 8; ++i) o[i] = ((v[i] - mean) * rstd * gg[i] + bb[i]) * 32.0f;
    unsigned int lo = 0, hi = 0;
    lo = (unsigned int)__builtin_amdgcn_cvt_pk_fp8_f32(o[0], o[1], 0, false);
    lo = (unsigned int)__builtin_amdgcn_cvt_pk_fp8_f32(o[2], o[3], (int)lo, true);
    hi = (unsigned int)__builtin_amdgcn_cvt_pk_fp8_f32(o[4], o[5], 0, false);
    hi = (unsigned int)__builtin_amdgcn_cvt_pk_fp8_f32(o[6], o[7], (int)hi, true);
    uint2 u; u.x = lo; u.y = hi;
    *(uint2*)(out + orow * kDIM + lane * 8) = u;
}

// ---------------- dynamic position bias MLP: 225 rows, 2->32->32->32->16 ----------------
__device__ inline void ln32_relu(float* h, const float* g, const float* b)
{
    float m = 0.f;
#pragma unroll
    for (int i = 0; i < 32; ++i) m += h[i];
    m *= (1.0f / 32.0f);
    float v = 0.f;
#pragma unroll
    for (int i = 0; i < 32; ++i) { float d = h[i] - m; v += d * d; }
    v *= (1.0f / 32.0f);
    float r = rsqrtf(v + 1e-5f);
#pragma unroll
    for (int i = 0; i < 32; ++i) h[i] = fmaxf((h[i] - m) * r * g[i] + b[i], 0.f);
}

__global__ __launch_bounds__(256)
void posmlp_k(const float* __restrict__ w0, const float* __restrict__ b0,
              const float* __restrict__ g0, const float* __restrict__ bb0,
              const float* __restrict__ w1, const float* __restrict__ b1,
              const float* __restrict__ g1, const float* __restrict__ bb1,
              const float* __restrict__ w2, const float* __restrict__ b2,
              const float* __restrict__ g2, const float* __restrict__ bb2,
              const float* __restrict__ w3, const float* __restrict__ b3,
              float* __restrict__ ptab)
{
    int r = threadIdx.x;
    if (r >= 225) return;
    float in0 = (float)(r / 15) - 7.0f;
    float in1 = (float)(r % 15) - 7.0f;
    float h[32], h2[32];
#pragma unroll
    for (int o = 0; o < 32; ++o) h[o] = w0[o * 2] * in0 + w0[o * 2 + 1] * in1 + b0[o];
    ln32_relu(h, g0, bb0);
#pragma unroll
    for (int o = 0; o < 32; ++o) {
        float s = b1[o];
#pragma unroll
        for (int i = 0; i < 32; ++i) s += w1[o * 32 + i] * h[i];
        h2[o] = s;
    }
    ln32_relu(h2, g1, bb1);
#pragma unroll
    for (int o = 0; o < 32; ++o) {
        float s = b2[o];
#pragma unroll
        for (int i = 0; i < 32; ++i) s += w2[o * 32 + i] * h2[i];
        h[o] = s;
    }
    ln32_relu(h, g2, bb2);
#pragma unroll
    for (int o = 0; o < 16; ++o) {
        float s = b3[o];
#pragma unroll
        for (int i = 0; i < 32; ++i) s += w3[o * 32 + i] * h[i];
        ptab[r * 16 + o] = s;
    }
}

// ---------------- attention: fp8 Q/K (QK^T via fp8 MFMA), bf16 V/P/PV, fp8 O out ----------------
// qkv row layout (2048 B): [Q 512 fp8 x32 | K 512 fp8 x32 | V 1024 bf16]
__global__ __launch_bounds__(256)
void attn_mfma_k(const unsigned char* __restrict__ qkv, const float* __restrict__ ptab,
                 unsigned char* __restrict__ obuf)
{
    const int g  = blockIdx.x >> 1;
    const int hb = blockIdx.x & 1;
    const int w  = threadIdx.x >> 6;
    const int lane = threadIdx.x & 63;
    const int c = lane & 15, q = lane >> 4;

    __shared__ float ptl[16][240];                 // ptab transposed [head][idx]
    __shared__ alignas(16) bf16 pl[4][4096];       // per-wave P (64x64), XOR-swizzled
    __shared__ alignas(16) bf16 vt[4][2048];       // per-wave V^T (32 d x 64 m), swizzled

    for (int i = threadIdx.x; i < 3600; i += 256)
        ptl[i & 15][i >> 4] = ptab[i];
    __syncthreads();

    const size_t rowb = (size_t)g * 64;
    bf16* pw = pl[w];
    char* vw = (char*)vt[w];

    for (int hh = 0; hh < 2; ++hh) {
        const int head = hb * 8 + hh * 4 + w;
        const unsigned char* qb = qkv + rowb * 2048 + head * 32;

        // V rows bf16: coalesced 16B loads (issued first; land under QK^T)
        const bf16* vbase = (const bf16*)(qb + 1024 + head * 32);  // +head*64 B total
        bf16x8 vrow[4];
#pragma unroll
        for (int l = 0; l < 4; ++l)
            vrow[l] = *(const bf16x8*)((const bf16*)((const char*)vbase + (size_t)lane * 2048) + l * 8);

        // Q/K fp8 frags (8B/lane)
        long aq[4], bk[4];
#pragma unroll
        for (int i = 0; i < 4; ++i) {
            aq[i] = *(const long*)(qb + (size_t)(i * 16 + c) * 2048 + q * 8);
            bk[i] = *(const long*)(qb + 512 + (size_t)(i * 16 + c) * 2048 + q * 8);
        }

        // S = Q K^T (fp8, K=32 in one MFMA per tile pair)
        f32x4_t s[4][4];
#pragma unroll
        for (int i = 0; i < 4; ++i)
#pragma unroll
            for (int j = 0; j < 4; ++j)
                s[i][j] = __builtin_amdgcn_mfma_f32_16x16x32_fp8_fp8(aq[i], bk[j],
                          (f32x4_t){0.f, 0.f, 0.f, 0.f}, 0, 0, 0);

        // V^T -> LDS (row d, offset m*2 XOR (d&7)<<4)
#pragma unroll
        for (int l = 0; l < 4; ++l)
#pragma unroll
            for (int j = 0; j < 8; ++j) {
                const int d = l * 8 + j;
                *(bf16*)(vw + d * 128 + ((lane * 2) ^ ((d & 7) << 4))) = vrow[l][j];
            }

        // scale (incl. 1/(32*32) fp8 descale) + rel-pos bias + row softmax
        const float scale = 0.17677669529663687f / 1024.0f;
        float inv[4][4];
#pragma unroll
        for (int i = 0; i < 4; ++i)
#pragma unroll
            for (int jj = 0; jj < 4; ++jj) {
                const int n = i * 16 + q * 4 + jj;
                const int na = n >> 3, nu = n & 7;
                float mx = -1e30f;
#pragma unroll
                for (int j = 0; j < 4; ++j) {
                    const int m = j * 16 + c;
                    const int idx = (na - (m >> 3) + 7) * 15 + (nu - (m & 7) + 7);
                    float v = s[i][j][jj] * scale + ptl[head][idx];
                    s[i][j][jj] = v;
                    mx = fmaxf(mx, v);
                }
#pragma unroll
                for (int off = 1; off < 16; off <<= 1) mx = fmaxf(mx, __shfl_xor(mx, off));
                float sum = 0.f;
#pragma unroll
                for (int j = 0; j < 4; ++j) {
                    float e = __expf(s[i][j][jj] - mx);
                    s[i][j][jj] = e; sum += e;
                }
#pragma unroll
                for (int off = 1; off < 16; off <<= 1) sum += __shfl_xor(sum, off);
                inv[i][jj] = 1.0f / sum;
            }

        // P -> LDS (bf16, swizzled: byte ^= (row&7)<<4)
#pragma unroll
        for (int i = 0; i < 4; ++i)
#pragma unroll
            for (int jj = 0; jj < 4; ++jj) {
                const int n = i * 16 + q * 4 + jj;
                const int swz = (n & 7) << 4;
#pragma unroll
                for (int j = 0; j < 4; ++j) {
                    const int m = j * 16 + c;
                    *(bf16*)((char*)pw + n * 128 + ((m * 2) ^ swz)) = (bf16)s[i][j][jj];
                }
            }

        // V B-frags from LDS V^T
        bf16x8 bv[2][2];
#pragma unroll
        for (int ks = 0; ks < 2; ++ks)
#pragma unroll
            for (int dt = 0; dt < 2; ++dt)
                bv[ks][dt] = *(const bf16x8*)(vw + (dt * 16 + c) * 128 +
                              ((ks * 64 + q * 16) ^ ((c & 7) << 4)));

        // O = P V (bf16)
        f32x4_t o[4][2];
#pragma unroll
        for (int i = 0; i < 4; ++i)
#pragma unroll
            for (int dt = 0; dt < 2; ++dt)
                o[i][dt] = (f32x4_t){0.f, 0.f, 0.f, 0.f};
#pragma unroll
        for (int ks = 0; ks < 2; ++ks)
#pragma unroll
            for (int i = 0; i < 4; ++i) {
                const int n = i * 16 + c;
                bf16x8 ap = *(const bf16x8*)((char*)pw + n * 128 +
                             ((ks * 64 + q * 16) ^ ((n & 7) << 4)));
#pragma unroll
                for (int dt = 0; dt < 2; ++dt)
                    o[i][dt] = __builtin_amdgcn_mfma_f32_16x16x32_bf16(ap, bv[ks][dt], o[i][dt], 0, 0, 0);
            }

        // normalize + store fp8 x32
        unsigned char* ob = obuf + rowb * 512 + head * 32;
#pragma unroll
        for (int i = 0; i < 4; ++i)
#pragma unroll
            for (int dt = 0; dt < 2; ++dt)
#pragma unroll
                for (int jj = 0; jj < 4; ++jj) {
                    const int n = i * 16 + q * 4 + jj;
                    float val = o[i][dt][jj] * inv[i][jj] * 32.0f;
                    int p8 = __builtin_amdgcn_cvt_pk_fp8_f32(val, val, 0, false);
                    ob[(size_t)n * 512 + dt * 16 + c] = (unsigned char)(p8 & 0xff);
                }
    }
}

// ---------------- fp8 GEMM: C = A_fp8[M,K] * Bw_fp8[N,K]^T * invs + bias, epilogues ----------------
// 128x128, BK=64 fp8 (64B rows, 4x16B slots), slot swizzle keyed (row>>1)&3 (R12-verified).
// MODE 0: QKV mixed out (gcol<1024: fp8 x32; else bf16), row stride 2048 B
// MODE 1: gelu -> fp8 x64 (MLP1) | MODE 2: +resid, ungroup -> f32 (proj) | MODE 3: +resid -> f32 (MLP2)
template<int MODE, int NBX>
__global__ __launch_bounds__(256, 2)
void gemm_fp8(const unsigned char* __restrict__ A, const unsigned char* __restrict__ Bw,
              const float* __restrict__ bias, const float* __restrict__ resid,
              void* __restrict__ outp, int N, int K, float invs)
{
    __shared__ alignas(16) unsigned char As[128 * 64];  // 8 KiB
    __shared__ alignas(16) unsigned char Bs[128 * 64];  // 8 KiB
    const int tid = threadIdx.x;
    const int lane = tid & 63;
    const int w = tid >> 6;
    const int wr = w >> 1, wc = w & 1;
    const int c = lane & 15, q = lane >> 4;

    const int bid = blockIdx.y * NBX + blockIdx.x;
    const int nwg = gridDim.y * NBX;
    const int swz = (bid & 7) * (nwg >> 3) + (bid >> 3);
    const int by = swz / NBX;
    const int bx = swz - by * NBX;
    const int rowBase = by * 128;
    const int colBase = bx * 128;

    f32x4_t acc[4][4];
#pragma unroll
    for (int m = 0; m < 4; ++m)
#pragma unroll
        for (int n = 0; n < 4; ++n)
            acc[m][n] = (f32x4_t){0.f, 0.f, 0.f, 0.f};

    const int f = (c >> 1) & 3;          // (row>>1)&3 for rows ...*16 + c
    const int hb8 = (q & 1) * 8;

    for (int kt = 0; kt < K; kt += 64) {
#pragma unroll
        for (int l = 0; l < 2; ++l) {
            const int cg = l * 256 + tid;
            const int row = cg >> 2;
            const int sg = (cg & 3) ^ ((cg >> 3) & 3);
            const int cu = l * 256 + (tid & 192);
            ASYNC_COPY16(A + (size_t)(rowBase + row) * K + kt + sg * 16, As + cu * 16);
            ASYNC_COPY16(Bw + (size_t)(colBase + row) * K + kt + sg * 16, Bs + cu * 16);
        }
        WAITV0();
        __syncthreads();
#pragma unroll
        for (int kk = 0; kk < 64; kk += 32) {
            const int sb = (((((kk >> 4) + (q >> 1)) ^ f) << 4)) + hb8;
            long af[4], bfr[4];
#pragma unroll
            for (int m = 0; m < 4; ++m) {
                const int row = wr * 64 + m * 16 + c;
                af[m] = *(const long*)((const char*)As + row * 64 + sb);
            }
#pragma unroll
            for (int n = 0; n < 4; ++n) {
                const int row = wc * 64 + n * 16 + c;
                bfr[n] = *(const long*)((const char*)Bs + row * 64 + sb);
            }
#pragma unroll
            for (int m = 0; m < 4; ++m)
#pragma unroll
                for (int n = 0; n < 4; ++n)
                    acc[m][n] = __builtin_amdgcn_mfma_f32_16x16x32_fp8_fp8(af[m], bfr[n], acc[m][n], 0, 0, 0);
        }
        __syncthreads();
    }

#pragma unroll
    for (int m = 0; m < 4; ++m) {
#pragma unroll
        for (int jj = 0; jj < 4; ++jj) {
            int grow = rowBase + wr * 64 + m * 16 + q * 4 + jj;
#pragma unroll
            for (int n = 0; n < 4; ++n) {
                int gcol = colBase + wc * 64 + n * 16 + c;
                float v = acc[m][n][jj] * invs + bias[gcol];
                if constexpr (MODE == 0) {
                    char* ob = (char*)outp;
                    if (gcol < 1024) {   // Q/K: fp8 x32 (tile-uniform branch)
                        int p8 = __builtin_amdgcn_cvt_pk_fp8_f32(v * 32.0f, v * 32.0f, 0, false);
                        ob[(size_t)grow * 2048 + gcol] = (char)(p8 & 0xff);
                    } else {             // V: bf16
                        *(bf16*)(ob + (size_t)grow * 2048 + 1024 + (size_t)(gcol - 1024) * 2) = (bf16)v;
                    }
                } else if constexpr (MODE == 1) {
                    float e = __expf(1.5957691216057308f * (v + 0.044715f * v * v * v));
                    v = v * (e / (1.0f + e));
                    int p8 = __builtin_amdgcn_cvt_pk_fp8_f32(v * 64.0f, v * 64.0f, 0, false);
                    ((unsigned char*)outp)[(size_t)grow * N + gcol] = (unsigned char)(p8 & 0xff);
                } else if constexpr (MODE == 2) {
                    int g = grow >> 6, ns = grow & 63;
                    int b = g >> 6, i = (g >> 3) & 7, j = g & 7;
                    int a = ns >> 3, u = ns & 7;
                    int t = b * 4096 + (a * 8 + i) * 64 + (u * 8 + j);
                    size_t oi = (size_t)t * 512 + gcol;
                    ((float*)outp)[oi] = resid[oi] + v;
                } else {
                    size_t oi = (size_t)grow * 512 + gcol;
                    ((float*)outp)[oi] = resid[oi] + v;
                }
            }
        }
    }
}

// ---------------- launcher ----------------
extern "C" void kernel_launch(void* const* d_in, const int* in_sizes, int n_in,
                              void* d_out, int out_size, void* d_ws, size_t ws_size,
                              hipStream_t stream)
{
    const float* x    = (const float*)d_in[0];
    const float* n1g  = (const float*)d_in[1];
    const float* n1b  = (const float*)d_in[2];
    const float* qkvw = (const float*)d_in[3];
    const float* qkvb = (const float*)d_in[4];
    const float* pjw  = (const float*)d_in[5];
    const float* pjb  = (const float*)d_in[6];
    const float* pw0  = (const float*)d_in[7];
    const float* pb0  = (const float*)d_in[8];
    const float* pg0  = (const float*)d_in[9];
    const float* pbb0 = (const float*)d_in[10];
    const float* pw1  = (const float*)d_in[11];
    const float* pb1  = (const float*)d_in[12];
    const float* pg1  = (const float*)d_in[13];
    const float* pbb1 = (const float*)d_in[14];
    const float* pw2  = (const float*)d_in[15];
    const float* pb2  = (const float*)d_in[16];
    const float* pg2  = (const float*)d_in[17];
    const float* pbb2 = (const float*)d_in[18];
    const float* pw3  = (const float*)d_in[19];
    const float* pb3  = (const float*)d_in[20];
    const float* n2g  = (const float*)d_in[21];
    const float* n2b  = (const float*)d_in[22];
    const float* w1   = (const float*)d_in[23];
    const float* b1   = (const float*)d_in[24];
    const float* w2   = (const float*)d_in[25];
    const float* b2   = (const float*)d_in[26];

    char* ws = (char*)d_ws;
    unsigned char* qkvw_f8 = (unsigned char*)(ws + OFF_QKVW);
    unsigned char* pjw_f8  = (unsigned char*)(ws + OFF_PROJW);
    unsigned char* w1_f8 = (unsigned char*)(ws + OFF_W1);
    unsigned char* w2_f8 = (unsigned char*)(ws + OFF_W2);
    float* ptab  = (float*)(ws + OFF_PTAB);
    unsigned char* bufA8 = (unsigned char*)(ws + OFF_A);   // qkv mixed / hidden fp8
    unsigned char* bufB8 = (unsigned char*)(ws + OFF_B);   // LN outs fp8 / attn-out fp8
    float* xout  = (float*)d_out;

    // weight casts (all fp8 x64)
    cast_fp8_k<<<(1536 * 512 / 4 + 255) / 256, 256, 0, stream>>>(qkvw, qkvw_f8, 1536 * 512 / 4);
    cast_fp8_k<<<(512 * 512 / 4 + 255) / 256, 256, 0, stream>>>(pjw, pjw_f8, 512 * 512 / 4);
    cast_fp8_k<<<(2048 * 512 / 4 + 255) / 256, 256, 0, stream>>>(w1, w1_f8, 2048 * 512 / 4);
    cast_fp8_k<<<(512 * 2048 / 4 + 255) / 256, 256, 0, stream>>>(w2, w2_f8, 512 * 2048 / 4);

    // pos-bias table
    posmlp_k<<<1, 256, 0, stream>>>(pw0, pb0, pg0, pbb0, pw1, pb1, pg1, pbb1,
                                    pw2, pb2, pg2, pbb2, pw3, pb3, ptab);

    // LN1 + group -> bufB (fp8 x32)
    ln_k<1><<<16384, 256, 0, stream>>>(x, n1g, n1b, bufB8);

    // QKV (fp8) -> bufA mixed layout [Qf8|Kf8|Vbf16], row stride 2048 B; invs = 1/(32*64)
    gemm_fp8<0, 12><<<dim3(12, 512), 256, 0, stream>>>(bufB8, qkvw_f8, qkvb, nullptr,
                                                       bufA8, 1536, 512, 1.0f / 2048.0f);

    // attention -> bufB (fp8 x32)
    attn_mfma_k<<<2048, 256, 0, stream>>>(bufA8, ptab, bufB8);

    // proj (fp8) + ungroup + residual(x) -> d_out (x1); invs = 1/(32*64)
    gemm_fp8<2, 4><<<dim3(4, 512), 256, 0, stream>>>(bufB8, pjw_f8, pjb, x,
                                                     xout, 512, 512, 1.0f / 2048.0f);

    // LN2 -> bufB (fp8 x32)
    ln_k<0><<<16384, 256, 0, stream>>>(xout, n2g, n2b, bufB8);

    // MLP1 (fp8) + gelu -> bufA as fp8 x64; invs = 1/(32*64)
    gemm_fp8<1, 16><<<dim3(16, 512), 256, 0, stream>>>(bufB8, w1_f8, b1, nullptr,
                                                       bufA8, 2048, 512, 1.0f / 2048.0f);

    // MLP2 (fp8) + residual(x1) -> d_out (in place); invs = 1/(64*64)
    gemm_fp8<3, 4><<<dim3(4, 512), 256, 0, stream>>>(bufA8, w2_f8, b2, xout,
                                                     xout, 512, 2048, 1.0f / 4096.0f);
}

// Round 15
// 698.519 us; speedup vs baseline: 1.3516x; 1.0358x over previous
//
#include <hip/hip_runtime.h>
#include <hip/hip_bf16.h>

typedef __bf16 bf16;
typedef __bf16 bf16x8 __attribute__((ext_vector_type(8)));
typedef __bf16 bf16x4 __attribute__((ext_vector_type(4)));
typedef float f32x4_t __attribute__((ext_vector_type(4)));

static constexpr int kDIM = 512;

// ---------------- ws layout (bytes) ----------------
static constexpr size_t OFF_QKVW = 0;                         // 1536*512 fp8
static constexpr size_t OFF_PROJW = 1572864;                  // 512*512 fp8
static constexpr size_t OFF_W1   = 2097152;                   // 2048*512 fp8
static constexpr size_t OFF_W2   = 4194304;                   // 512*2048 fp8
static constexpr size_t OFF_PTAB = 6291456;                   // 225*16 f32
static constexpr size_t OFF_A    = 8388608;                   // qkv mixed (134MB) / hidden fp8
static constexpr size_t OFF_B    = 276824064;                 // ln fp8 / attn-out fp8

typedef __attribute__((address_space(3))) uint32_t lds_u32_t;
typedef __attribute__((address_space(1))) const uint32_t glb_u32_t;
#define ASYNC_COPY16(gp, lp) __builtin_amdgcn_global_load_lds((glb_u32_t*)(gp), (lds_u32_t*)(lp), 16, 0, 0)
#define WAITV0() asm volatile("s_waitcnt vmcnt(0)" ::: "memory")

// ---------------- fp32 -> fp8 e4m3 cast with x64 scale ----------------
__global__ void cast_fp8_k(const float* __restrict__ in, unsigned char* __restrict__ out, int n4)
{
    int i = blockIdx.x * blockDim.x + threadIdx.x;
    if (i < n4) {
        float4 v = ((const float4*)in)[i];
        int p = __builtin_amdgcn_cvt_pk_fp8_f32(v.x * 64.0f, v.y * 64.0f, 0, false);
        p = __builtin_amdgcn_cvt_pk_fp8_f32(v.z * 64.0f, v.w * 64.0f, p, true);
        ((unsigned int*)out)[i] = (unsigned int)p;
    }
}

// ---------------- LayerNorm (+ optional LDA grouping) -> fp8 x32 ----------------
template<int GROUP>
__global__ __launch_bounds__(256)
void ln_k(const float* __restrict__ x, const float* __restrict__ gw,
          const float* __restrict__ bw, unsigned char* __restrict__ out)
{
    const int t = blockIdx.x * 4 + (threadIdx.x >> 6);
    const int lane = threadIdx.x & 63;
    const float* xp = x + (size_t)t * kDIM + lane * 8;
    float4 p0 = *(const float4*)xp;
    float4 p1 = *(const float4*)(xp + 4);
    float v[8] = {p0.x, p0.y, p0.z, p0.w, p1.x, p1.y, p1.z, p1.w};
    float s = 0.f;
#pragma unroll
    for (int i = 0; i < 8; ++i) s += v[i];
#pragma unroll
    for (int off = 32; off > 0; off >>= 1) s += __shfl_xor(s, off);
    const float mean = s * (1.0f / 512.0f);
    float q = 0.f;
#pragma unroll
    for (int i = 0; i < 8; ++i) { float d = v[i] - mean; q += d * d; }
#pragma unroll
    for (int off = 32; off > 0; off >>= 1) q += __shfl_xor(q, off);
    const float rstd = rsqrtf(q * (1.0f / 512.0f) + 1e-5f);
    size_t orow;
    if (GROUP) {
        int b = t >> 12, r = (t >> 6) & 63, c = t & 63;
        int g = b * 64 + (r & 7) * 8 + (c & 7);
        int n = (r >> 3) * 8 + (c >> 3);
        orow = (size_t)g * 64 + n;
    } else {
        orow = t;
    }
    float4 g0 = *(const float4*)(gw + lane * 8);
    float4 g1 = *(const float4*)(gw + lane * 8 + 4);
    float4 b0 = *(const float4*)(bw + lane * 8);
    float4 b1 = *(const float4*)(bw + lane * 8 + 4);
    float gg[8] = {g0.x, g0.y, g0.z, g0.w, g1.x, g1.y, g1.z, g1.w};
    float bb[8] = {b0.x, b0.y, b0.z, b0.w, b1.x, b1.y, b1.z, b1.w};
    float o[8];
#pragma unroll
    for (int i = 0; i < 8; ++i) o[i] = ((v[i] - mean) * rstd * gg[i] + bb[i]) * 32.0f;
    unsigned int lo = 0, hi = 0;
    lo = (unsigned int)__builtin_amdgcn_cvt_pk_fp8_f32(o[0], o[1], 0, false);
    lo = (unsigned int)__builtin_amdgcn_cvt_pk_fp8_f32(o[2], o[3], (int)lo, true);
    hi = (unsigned int)__builtin_amdgcn_cvt_pk_fp8_f32(o[4], o[5], 0, false);
    hi = (unsigned int)__builtin_amdgcn_cvt_pk_fp8_f32(o[6], o[7], (int)hi, true);
    uint2 u; u.x = lo; u.y = hi;
    *(uint2*)(out + orow * kDIM + lane * 8) = u;
}

// ---------------- dynamic position bias MLP: 225 rows, 2->32->32->32->16 ----------------
__device__ inline void ln32_relu(float* h, const float* g, const float* b)
{
    float m = 0.f;
#pragma unroll
    for (int i = 0; i < 32; ++i) m += h[i];
    m *= (1.0f / 32.0f);
    float v = 0.f;
#pragma unroll
    for (int i = 0; i < 32; ++i) { float d = h[i] - m; v += d * d; }
    v *= (1.0f / 32.0f);
    float r = rsqrtf(v + 1e-5f);
#pragma unroll
    for (int i = 0; i < 32; ++i) h[i] = fmaxf((h[i] - m) * r * g[i] + b[i], 0.f);
}

__global__ __launch_bounds__(256)
void posmlp_k(const float* __restrict__ w0, const float* __restrict__ b0,
              const float* __restrict__ g0, const float* __restrict__ bb0,
              const float* __restrict__ w1, const float* __restrict__ b1,
              const float* __restrict__ g1, const float* __restrict__ bb1,
              const float* __restrict__ w2, const float* __restrict__ b2,
              const float* __restrict__ g2, const float* __restrict__ bb2,
              const float* __restrict__ w3, const float* __restrict__ b3,
              float* __restrict__ ptab)
{
    int r = threadIdx.x;
    if (r >= 225) return;
    float in0 = (float)(r / 15) - 7.0f;
    float in1 = (float)(r % 15) - 7.0f;
    float h[32], h2[32];
#pragma unroll
    for (int o = 0; o < 32; ++o) h[o] = w0[o * 2] * in0 + w0[o * 2 + 1] * in1 + b0[o];
    ln32_relu(h, g0, bb0);
#pragma unroll
    for (int o = 0; o < 32; ++o) {
        float s = b1[o];
#pragma unroll
        for (int i = 0; i < 32; ++i) s += w1[o * 32 + i] * h[i];
        h2[o] = s;
    }
    ln32_relu(h2, g1, bb1);
#pragma unroll
    for (int o = 0; o < 32; ++o) {
        float s = b2[o];
#pragma unroll
        for (int i = 0; i < 32; ++i) s += w2[o * 32 + i] * h2[i];
        h[o] = s;
    }
    ln32_relu(h, g2, bb2);
#pragma unroll
    for (int o = 0; o < 16; ++o) {
        float s = b3[o];
#pragma unroll
        for (int i = 0; i < 32; ++i) s += w3[o * 32 + i] * h[i];
        ptab[r * 16 + o] = s;
    }
}

// ---------------- attention: fp8 Q/K (QK^T via fp8 MFMA), bf16 V/P/PV, fp8 O out ----------------
// qkv row layout (2048 B): [Q 512 fp8 x32 | K 512 fp8 x32 | V 1024 bf16]
__global__ __launch_bounds__(256)
void attn_mfma_k(const unsigned char* __restrict__ qkv, const float* __restrict__ ptab,
                 unsigned char* __restrict__ obuf)
{
    const int g  = blockIdx.x >> 1;
    const int hb = blockIdx.x & 1;
    const int w  = threadIdx.x >> 6;
    const int lane = threadIdx.x & 63;
    const int c = lane & 15, q = lane >> 4;

    __shared__ float ptl[16][240];                 // ptab transposed [head][idx]
    __shared__ alignas(16) bf16 pl[4][4096];       // per-wave P (64x64), XOR-swizzled
    __shared__ alignas(16) bf16 vt[4][2048];       // per-wave V^T (32 d x 64 m), swizzled

    for (int i = threadIdx.x; i < 3600; i += 256)
        ptl[i & 15][i >> 4] = ptab[i];
    __syncthreads();

    const size_t rowb = (size_t)g * 64;
    bf16* pw = pl[w];
    char* vw = (char*)vt[w];

    for (int hh = 0; hh < 2; ++hh) {
        const int head = hb * 8 + hh * 4 + w;
        const unsigned char* qb = qkv + rowb * 2048 + head * 32;

        // V rows bf16: coalesced 16B loads (issued first; land under QK^T)
        const bf16* vbase = (const bf16*)(qb + 1024 + head * 32);  // +head*64 B total
        bf16x8 vrow[4];
#pragma unroll
        for (int l = 0; l < 4; ++l)
            vrow[l] = *(const bf16x8*)((const bf16*)((const char*)vbase + (size_t)lane * 2048) + l * 8);

        // Q/K fp8 frags (8B/lane)
        long aq[4], bk[4];
#pragma unroll
        for (int i = 0; i < 4; ++i) {
            aq[i] = *(const long*)(qb + (size_t)(i * 16 + c) * 2048 + q * 8);
            bk[i] = *(const long*)(qb + 512 + (size_t)(i * 16 + c) * 2048 + q * 8);
        }

        // S = Q K^T (fp8, K=32 in one MFMA per tile pair)
        f32x4_t s[4][4];
#pragma unroll
        for (int i = 0; i < 4; ++i)
#pragma unroll
            for (int j = 0; j < 4; ++j)
                s[i][j] = __builtin_amdgcn_mfma_f32_16x16x32_fp8_fp8(aq[i], bk[j],
                          (f32x4_t){0.f, 0.f, 0.f, 0.f}, 0, 0, 0);

        // V^T -> LDS (row d, offset m*2 XOR (d&7)<<4)
#pragma unroll
        for (int l = 0; l < 4; ++l)
#pragma unroll
            for (int j = 0; j < 8; ++j) {
                const int d = l * 8 + j;
                *(bf16*)(vw + d * 128 + ((lane * 2) ^ ((d & 7) << 4))) = vrow[l][j];
            }

        // scale (incl. 1/(32*32) fp8 descale) + rel-pos bias + row softmax
        const float scale = 0.17677669529663687f / 1024.0f;
        float inv[4][4];
#pragma unroll
        for (int i = 0; i < 4; ++i)
#pragma unroll
            for (int jj = 0; jj < 4; ++jj) {
                const int n = i * 16 + q * 4 + jj;
                const int na = n >> 3, nu = n & 7;
                float mx = -1e30f;
#pragma unroll
                for (int j = 0; j < 4; ++j) {
                    const int m = j * 16 + c;
                    const int idx = (na - (m >> 3) + 7) * 15 + (nu - (m & 7) + 7);
                    float v = s[i][j][jj] * scale + ptl[head][idx];
                    s[i][j][jj] = v;
                    mx = fmaxf(mx, v);
                }
#pragma unroll
                for (int off = 1; off < 16; off <<= 1) mx = fmaxf(mx, __shfl_xor(mx, off));
                float sum = 0.f;
#pragma unroll
                for (int j = 0; j < 4; ++j) {
                    float e = __expf(s[i][j][jj] - mx);
                    s[i][j][jj] = e; sum += e;
                }
#pragma unroll
                for (int off = 1; off < 16; off <<= 1) sum += __shfl_xor(sum, off);
                inv[i][jj] = 1.0f / sum;
            }

        // P -> LDS (bf16, swizzled: byte ^= (row&7)<<4)
#pragma unroll
        for (int i = 0; i < 4; ++i)
#pragma unroll
            for (int jj = 0; jj < 4; ++jj) {
                const int n = i * 16 + q * 4 + jj;
                const int swz = (n & 7) << 4;
#pragma unroll
                for (int j = 0; j < 4; ++j) {
                    const int m = j * 16 + c;
                    *(bf16*)((char*)pw + n * 128 + ((m * 2) ^ swz)) = (bf16)s[i][j][jj];
                }
            }

        // V B-frags from LDS V^T
        bf16x8 bv[2][2];
#pragma unroll
        for (int ks = 0; ks < 2; ++ks)
#pragma unroll
            for (int dt = 0; dt < 2; ++dt)
                bv[ks][dt] = *(const bf16x8*)(vw + (dt * 16 + c) * 128 +
                              ((ks * 64 + q * 16) ^ ((c & 7) << 4)));

        // O = P V (bf16)
        f32x4_t o[4][2];
#pragma unroll
        for (int i = 0; i < 4; ++i)
#pragma unroll
            for (int dt = 0; dt < 2; ++dt)
                o[i][dt] = (f32x4_t){0.f, 0.f, 0.f, 0.f};
#pragma unroll
        for (int ks = 0; ks < 2; ++ks)
#pragma unroll
            for (int i = 0; i < 4; ++i) {
                const int n = i * 16 + c;
                bf16x8 ap = *(const bf16x8*)((char*)pw + n * 128 +
                             ((ks * 64 + q * 16) ^ ((n & 7) << 4)));
#pragma unroll
                for (int dt = 0; dt < 2; ++dt)
                    o[i][dt] = __builtin_amdgcn_mfma_f32_16x16x32_bf16(ap, bv[ks][dt], o[i][dt], 0, 0, 0);
            }

        // normalize + store fp8 x32
        unsigned char* ob = obuf + rowb * 512 + head * 32;
#pragma unroll
        for (int i = 0; i < 4; ++i)
#pragma unroll
            for (int dt = 0; dt < 2; ++dt)
#pragma unroll
                for (int jj = 0; jj < 4; ++jj) {
                    const int n = i * 16 + q * 4 + jj;
                    float val = o[i][dt][jj] * inv[i][jj] * 32.0f;
                    int p8 = __builtin_amdgcn_cvt_pk_fp8_f32(val, val, 0, false);
                    ob[(size_t)n * 512 + dt * 16 + c] = (unsigned char)(p8 & 0xff);
                }
    }
}

// ---------------- fp8 GEMM: C = A_fp8[M,K] * Bw_fp8[N,K]^T * invs + bias, epilogues ----------------
// BK=128 (fp8 -> 128 B rows, 8x16B slots): 4 barrier-drains per K=512 instead of 8,
// LDS still 32 KiB total (R7-proven footprint/occupancy). Slot swizzle key = row&7
// (read side: c&7, lane-constant); phys slot = logical ((kk>>4)+(q>>1)) ^ key.
// Bank audit: uniform 4 lanes per 2-bank position = the b64 wave-read minimum.
// Sync = R7-proven vmcnt(0)+__syncthreads pair. T1 bijective XCD swizzle.
// MODE 0: QKV mixed out (gcol<1024: fp8 x32; else bf16), row stride 2048 B
// MODE 1: gelu -> fp8 x64 (MLP1) | MODE 2: +resid, ungroup -> f32 (proj) | MODE 3: +resid -> f32 (MLP2)
template<int MODE, int NBX>
__global__ __launch_bounds__(256, 2)
void gemm_fp8(const unsigned char* __restrict__ A, const unsigned char* __restrict__ Bw,
              const float* __restrict__ bias, const float* __restrict__ resid,
              void* __restrict__ outp, int N, int K, float invs)
{
    __shared__ alignas(16) unsigned char As[128 * 128];  // 16 KiB
    __shared__ alignas(16) unsigned char Bs[128 * 128];  // 16 KiB
    const int tid = threadIdx.x;
    const int lane = tid & 63;
    const int w = tid >> 6;
    const int wr = w >> 1, wc = w & 1;
    const int c = lane & 15, q = lane >> 4;

    const int bid = blockIdx.y * NBX + blockIdx.x;
    const int nwg = gridDim.y * NBX;
    const int swz = (bid & 7) * (nwg >> 3) + (bid >> 3);
    const int by = swz / NBX;
    const int bx = swz - by * NBX;
    const int rowBase = by * 128;
    const int colBase = bx * 128;

    f32x4_t acc[4][4];
#pragma unroll
    for (int m = 0; m < 4; ++m)
#pragma unroll
        for (int n = 0; n < 4; ++n)
            acc[m][n] = (f32x4_t){0.f, 0.f, 0.f, 0.f};

    const int key = c & 7;               // row&7 for rows ...*16 + c
    const int hb8 = (q & 1) * 8;

    for (int kt = 0; kt < K; kt += 128) {
        // stage: 4 chunks/thread each for A,B; chunk cg -> row=cg>>3, phys slot=cg&7;
        // source slot pre-swizzled: (cg&7) ^ (row&7) = (cg&7) ^ ((cg>>3)&7)
#pragma unroll
        for (int l = 0; l < 4; ++l) {
            const int cg = l * 256 + tid;
            const int row = cg >> 3;
            const int sg = (cg & 7) ^ (row & 7);
            const int cu = l * 256 + (tid & 192);
            ASYNC_COPY16(A + (size_t)(rowBase + row) * K + kt + sg * 16, As + cu * 16);
            ASYNC_COPY16(Bw + (size_t)(colBase + row) * K + kt + sg * 16, Bs + cu * 16);
        }
        WAITV0();
        __syncthreads();
#pragma unroll
        for (int kk = 0; kk < 128; kk += 32) {
            const int sb = ((((kk >> 4) + (q >> 1)) ^ key) << 4) + hb8;
            long af[4], bfr[4];
#pragma unroll
            for (int m = 0; m < 4; ++m) {
                const int row = wr * 64 + m * 16 + c;
                af[m] = *(const long*)((const char*)As + row * 128 + sb);
            }
#pragma unroll
            for (int n = 0; n < 4; ++n) {
                const int row = wc * 64 + n * 16 + c;
                bfr[n] = *(const long*)((const char*)Bs + row * 128 + sb);
            }
#pragma unroll
            for (int m = 0; m < 4; ++m)
#pragma unroll
                for (int n = 0; n < 4; ++n)
                    acc[m][n] = __builtin_amdgcn_mfma_f32_16x16x32_fp8_fp8(af[m], bfr[n], acc[m][n], 0, 0, 0);
        }
        __syncthreads();
    }

#pragma unroll
    for (int m = 0; m < 4; ++m) {
#pragma unroll
        for (int jj = 0; jj < 4; ++jj) {
            int grow = rowBase + wr * 64 + m * 16 + q * 4 + jj;
#pragma unroll
            for (int n = 0; n < 4; ++n) {
                int gcol = colBase + wc * 64 + n * 16 + c;
                float v = acc[m][n][jj] * invs + bias[gcol];
                if constexpr (MODE == 0) {
                    char* ob = (char*)outp;
                    if (gcol < 1024) {   // Q/K: fp8 x32 (tile-uniform branch)
                        int p8 = __builtin_amdgcn_cvt_pk_fp8_f32(v * 32.0f, v * 32.0f, 0, false);
                        ob[(size_t)grow * 2048 + gcol] = (char)(p8 & 0xff);
                    } else {             // V: bf16
                        *(bf16*)(ob + (size_t)grow * 2048 + 1024 + (size_t)(gcol - 1024) * 2) = (bf16)v;
                    }
                } else if constexpr (MODE == 1) {
                    float e = __expf(1.5957691216057308f * (v + 0.044715f * v * v * v));
                    v = v * (e / (1.0f + e));
                    int p8 = __builtin_amdgcn_cvt_pk_fp8_f32(v * 64.0f, v * 64.0f, 0, false);
                    ((unsigned char*)outp)[(size_t)grow * N + gcol] = (unsigned char)(p8 & 0xff);
                } else if constexpr (MODE == 2) {
                    int g = grow >> 6, ns = grow & 63;
                    int b = g >> 6, i = (g >> 3) & 7, j = g & 7;
                    int a = ns >> 3, u = ns & 7;
                    int t = b * 4096 + (a * 8 + i) * 64 + (u * 8 + j);
                    size_t oi = (size_t)t * 512 + gcol;
                    ((float*)outp)[oi] = resid[oi] + v;
                } else {
                    size_t oi = (size_t)grow * 512 + gcol;
                    ((float*)outp)[oi] = resid[oi] + v;
                }
            }
        }
    }
}

// ---------------- launcher ----------------
extern "C" void kernel_launch(void* const* d_in, const int* in_sizes, int n_in,
                              void* d_out, int out_size, void* d_ws, size_t ws_size,
                              hipStream_t stream)
{
    const float* x    = (const float*)d_in[0];
    const float* n1g  = (const float*)d_in[1];
    const float* n1b  = (const float*)d_in[2];
    const float* qkvw = (const float*)d_in[3];
    const float* qkvb = (const float*)d_in[4];
    const float* pjw  = (const float*)d_in[5];
    const float* pjb  = (const float*)d_in[6];
    const float* pw0  = (const float*)d_in[7];
    const float* pb0  = (const float*)d_in[8];
    const float* pg0  = (const float*)d_in[9];
    const float* pbb0 = (const float*)d_in[10];
    const float* pw1  = (const float*)d_in[11];
    const float* pb1  = (const float*)d_in[12];
    const float* pg1  = (const float*)d_in[13];
    const float* pbb1 = (const float*)d_in[14];
    const float* pw2  = (const float*)d_in[15];
    const float* pb2  = (const float*)d_in[16];
    const float* pg2  = (const float*)d_in[17];
    const float* pbb2 = (const float*)d_in[18];
    const float* pw3  = (const float*)d_in[19];
    const float* pb3  = (const float*)d_in[20];
    const float* n2g  = (const float*)d_in[21];
    const float* n2b  = (const float*)d_in[22];
    const float* w1   = (const float*)d_in[23];
    const float* b1   = (const float*)d_in[24];
    const float* w2   = (const float*)d_in[25];
    const float* b2   = (const float*)d_in[26];

    char* ws = (char*)d_ws;
    unsigned char* qkvw_f8 = (unsigned char*)(ws + OFF_QKVW);
    unsigned char* pjw_f8  = (unsigned char*)(ws + OFF_PROJW);
    unsigned char* w1_f8 = (unsigned char*)(ws + OFF_W1);
    unsigned char* w2_f8 = (unsigned char*)(ws + OFF_W2);
    float* ptab  = (float*)(ws + OFF_PTAB);
    unsigned char* bufA8 = (unsigned char*)(ws + OFF_A);   // qkv mixed / hidden fp8
    unsigned char* bufB8 = (unsigned char*)(ws + OFF_B);   // LN outs fp8 / attn-out fp8
    float* xout  = (float*)d_out;

    // weight casts (all fp8 x64)
    cast_fp8_k<<<(1536 * 512 / 4 + 255) / 256, 256, 0, stream>>>(qkvw, qkvw_f8, 1536 * 512 / 4);
    cast_fp8_k<<<(512 * 512 / 4 + 255) / 256, 256, 0, stream>>>(pjw, pjw_f8, 512 * 512 / 4);
    cast_fp8_k<<<(2048 * 512 / 4 + 255) / 256, 256, 0, stream>>>(w1, w1_f8, 2048 * 512 / 4);
    cast_fp8_k<<<(512 * 2048 / 4 + 255) / 256, 256, 0, stream>>>(w2, w2_f8, 512 * 2048 / 4);

    // pos-bias table
    posmlp_k<<<1, 256, 0, stream>>>(pw0, pb0, pg0, pbb0, pw1, pb1, pg1, pbb1,
                                    pw2, pb2, pg2, pbb2, pw3, pb3, ptab);

    // LN1 + group -> bufB (fp8 x32)
    ln_k<1><<<16384, 256, 0, stream>>>(x, n1g, n1b, bufB8);

    // QKV (fp8) -> bufA mixed layout [Qf8|Kf8|Vbf16], row stride 2048 B; invs = 1/(32*64)
    gemm_fp8<0, 12><<<dim3(12, 512), 256, 0, stream>>>(bufB8, qkvw_f8, qkvb, nullptr,
                                                       bufA8, 1536, 512, 1.0f / 2048.0f);

    // attention -> bufB (fp8 x32)
    attn_mfma_k<<<2048, 256, 0, stream>>>(bufA8, ptab, bufB8);

    // proj (fp8) + ungroup + residual(x) -> d_out (x1); invs = 1/(32*64)
    gemm_fp8<2, 4><<<dim3(4, 512), 256, 0, stream>>>(bufB8, pjw_f8, pjb, x,
                                                     xout, 512, 512, 1.0f / 2048.0f);

    // LN2 -> bufB (fp8 x32)
    ln_k<0><<<16384, 256, 0, stream>>>(xout, n2g, n2b, bufB8);

    // MLP1 (fp8) + gelu -> bufA as fp8 x64; invs = 1/(32*64)
    gemm_fp8<1, 16><<<dim3(16, 512), 256, 0, stream>>>(bufB8, w1_f8, b1, nullptr,
                                                       bufA8, 2048, 512, 1.0f / 2048.0f);

    // MLP2 (fp8) + residual(x1) -> d_out (in place); invs = 1/(64*64)
    gemm_fp8<3, 4><<<dim3(4, 512), 256, 0, stream>>>(bufA8, w2_f8, b2, xout,
                                                     xout, 512, 2048, 1.0f / 4096.0f);
}

// Round 17
// 688.302 us; speedup vs baseline: 1.3717x; 1.0148x over previous
//
#include <hip/hip_runtime.h>
#include <hip/hip_bf16.h>

typedef __bf16 bf16;
typedef __bf16 bf16x8 __attribute__((ext_vector_type(8)));
typedef __bf16 bf16x4 __attribute__((ext_vector_type(4)));
typedef float f32x4_t __attribute__((ext_vector_type(4)));

static constexpr int kDIM = 512;

// ---------------- ws layout (bytes) ----------------
static constexpr size_t OFF_QKVW = 0;                         // 1536*512 fp8
static constexpr size_t OFF_PROJW = 1572864;                  // 512*512 fp8
static constexpr size_t OFF_W1   = 2097152;                   // 2048*512 fp8
static constexpr size_t OFF_W2   = 4194304;                   // 512*2048 fp8
static constexpr size_t OFF_PTAB = 6291456;                   // 225*16 f32
static constexpr size_t OFF_A    = 8388608;                   // qkv mixed (134MB) / hidden fp8
static constexpr size_t OFF_B    = 276824064;                 // ln fp8 / attn-out fp8

typedef __attribute__((address_space(3))) uint32_t lds_u32_t;
typedef __attribute__((address_space(1))) const uint32_t glb_u32_t;
#define ASYNC_COPY16(gp, lp) __builtin_amdgcn_global_load_lds((glb_u32_t*)(gp), (lds_u32_t*)(lp), 16, 0, 0)
#define WAITV0() asm volatile("s_waitcnt vmcnt(0)" ::: "memory")

// ---------------- fp32 -> fp8 e4m3 cast with x64 scale ----------------
__global__ void cast_fp8_k(const float* __restrict__ in, unsigned char* __restrict__ out, int n4)
{
    int i = blockIdx.x * blockDim.x + threadIdx.x;
    if (i < n4) {
        float4 v = ((const float4*)in)[i];
        int p = __builtin_amdgcn_cvt_pk_fp8_f32(v.x * 64.0f, v.y * 64.0f, 0, false);
        p = __builtin_amdgcn_cvt_pk_fp8_f32(v.z * 64.0f, v.w * 64.0f, p, true);
        ((unsigned int*)out)[i] = (unsigned int)p;
    }
}

// ---------------- LayerNorm (+ optional LDA grouping) -> fp8 x32 ----------------
template<int GROUP>
__global__ __launch_bounds__(256)
void ln_k(const float* __restrict__ x, const float* __restrict__ gw,
          const float* __restrict__ bw, unsigned char* __restrict__ out)
{
    const int t = blockIdx.x * 4 + (threadIdx.x >> 6);
    const int lane = threadIdx.x & 63;
    const float* xp = x + (size_t)t * kDIM + lane * 8;
    float4 p0 = *(const float4*)xp;
    float4 p1 = *(const float4*)(xp + 4);
    float v[8] = {p0.x, p0.y, p0.z, p0.w, p1.x, p1.y, p1.z, p1.w};
    float s = 0.f;
#pragma unroll
    for (int i = 0; i < 8; ++i) s += v[i];
#pragma unroll
    for (int off = 32; off > 0; off >>= 1) s += __shfl_xor(s, off);
    const float mean = s * (1.0f / 512.0f);
    float q = 0.f;
#pragma unroll
    for (int i = 0; i < 8; ++i) { float d = v[i] - mean; q += d * d; }
#pragma unroll
    for (int off = 32; off > 0; off >>= 1) q += __shfl_xor(q, off);
    const float rstd = rsqrtf(q * (1.0f / 512.0f) + 1e-5f);
    size_t orow;
    if (GROUP) {
        int b = t >> 12, r = (t >> 6) & 63, c = t & 63;
        int g = b * 64 + (r & 7) * 8 + (c & 7);
        int n = (r >> 3) * 8 + (c >> 3);
        orow = (size_t)g * 64 + n;
    } else {
        orow = t;
    }
    float4 g0 = *(const float4*)(gw + lane * 8);
    float4 g1 = *(const float4*)(gw + lane * 8 + 4);
    float4 b0 = *(const float4*)(bw + lane * 8);
    float4 b1 = *(const float4*)(bw + lane * 8 + 4);
    float gg[8] = {g0.x, g0.y, g0.z, g0.w, g1.x, g1.y, g1.z, g1.w};
    float bb[8] = {b0.x, b0.y, b0.z, b0.w, b1.x, b1.y, b1.z, b1.w};
    float o[8];
#pragma unroll
    for (int i = 0; i < 8; ++i) o[i] = ((v[i] - mean) * rstd * gg[i] + bb[i]) * 32.0f;
    unsigned int lo = 0, hi = 0;
    lo = (unsigned int)__builtin_amdgcn_cvt_pk_fp8_f32(o[0], o[1], 0, false);
    lo = (unsigned int)__builtin_amdgcn_cvt_pk_fp8_f32(o[2], o[3], (int)lo, true);
    hi = (unsigned int)__builtin_amdgcn_cvt_pk_fp8_f32(o[4], o[5], 0, false);
    hi = (unsigned int)__builtin_amdgcn_cvt_pk_fp8_f32(o[6], o[7], (int)hi, true);
    uint2 u; u.x = lo; u.y = hi;
    *(uint2*)(out + orow * kDIM + lane * 8) = u;
}

// ---------------- dynamic position bias MLP: 225 rows, 2->32->32->32->16 ----------------
__device__ inline void ln32_relu(float* h, const float* g, const float* b)
{
    float m = 0.f;
#pragma unroll
    for (int i = 0; i < 32; ++i) m += h[i];
    m *= (1.0f / 32.0f);
    float v = 0.f;
#pragma unroll
    for (int i = 0; i < 32; ++i) { float d = h[i] - m; v += d * d; }
    v *= (1.0f / 32.0f);
    float r = rsqrtf(v + 1e-5f);
#pragma unroll
    for (int i = 0; i < 32; ++i) h[i] = fmaxf((h[i] - m) * r * g[i] + b[i], 0.f);
}

__global__ __launch_bounds__(256)
void posmlp_k(const float* __restrict__ w0, const float* __restrict__ b0,
              const float* __restrict__ g0, const float* __restrict__ bb0,
              const float* __restrict__ w1, const float* __restrict__ b1,
              const float* __restrict__ g1, const float* __restrict__ bb1,
              const float* __restrict__ w2, const float* __restrict__ b2,
              const float* __restrict__ g2, const float* __restrict__ bb2,
              const float* __restrict__ w3, const float* __restrict__ b3,
              float* __restrict__ ptab)
{
    int r = threadIdx.x;
    if (r >= 225) return;
    float in0 = (float)(r / 15) - 7.0f;
    float in1 = (float)(r % 15) - 7.0f;
    float h[32], h2[32];
#pragma unroll
    for (int o = 0; o < 32; ++o) h[o] = w0[o * 2] * in0 + w0[o * 2 + 1] * in1 + b0[o];
    ln32_relu(h, g0, bb0);
#pragma unroll
    for (int o = 0; o < 32; ++o) {
        float s = b1[o];
#pragma unroll
        for (int i = 0; i < 32; ++i) s += w1[o * 32 + i] * h[i];
        h2[o] = s;
    }
    ln32_relu(h2, g1, bb1);
#pragma unroll
    for (int o = 0; o < 32; ++o) {
        float s = b2[o];
#pragma unroll
        for (int i = 0; i < 32; ++i) s += w2[o * 32 + i] * h2[i];
        h[o] = s;
    }
    ln32_relu(h, g2, bb2);
#pragma unroll
    for (int o = 0; o < 16; ++o) {
        float s = b3[o];
#pragma unroll
        for (int i = 0; i < 32; ++i) s += w3[o * 32 + i] * h[i];
        ptab[r * 16 + o] = s;
    }
}

// ---------------- attention: fp8 Q/K (QK^T via fp8 MFMA), bf16 V/P/PV, fp8 O out ----------------
// qkv row layout (2048 B): [Q 512 fp8 x32 | K 512 fp8 x32 | V 1024 bf16]
__global__ __launch_bounds__(256)
void attn_mfma_k(const unsigned char* __restrict__ qkv, const float* __restrict__ ptab,
                 unsigned char* __restrict__ obuf)
{
    const int g  = blockIdx.x >> 1;
    const int hb = blockIdx.x & 1;
    const int w  = threadIdx.x >> 6;
    const int lane = threadIdx.x & 63;
    const int c = lane & 15, q = lane >> 4;

    __shared__ float ptl[16][240];                 // ptab transposed [head][idx]
    __shared__ alignas(16) bf16 pl[4][4096];       // per-wave P (64x64), XOR-swizzled
    __shared__ alignas(16) bf16 vt[4][2048];       // per-wave V^T (32 d x 64 m), swizzled

    for (int i = threadIdx.x; i < 3600; i += 256)
        ptl[i & 15][i >> 4] = ptab[i];
    __syncthreads();

    const size_t rowb = (size_t)g * 64;
    bf16* pw = pl[w];
    char* vw = (char*)vt[w];

    for (int hh = 0; hh < 2; ++hh) {
        const int head = hb * 8 + hh * 4 + w;
        const unsigned char* qb = qkv + rowb * 2048 + head * 32;

        // V rows bf16: coalesced 16B loads (issued first; land under QK^T)
        const bf16* vbase = (const bf16*)(qb + 1024 + head * 32);  // +head*64 B total
        bf16x8 vrow[4];
#pragma unroll
        for (int l = 0; l < 4; ++l)
            vrow[l] = *(const bf16x8*)((const bf16*)((const char*)vbase + (size_t)lane * 2048) + l * 8);

        // Q/K fp8 frags (8B/lane)
        long aq[4], bk[4];
#pragma unroll
        for (int i = 0; i < 4; ++i) {
            aq[i] = *(const long*)(qb + (size_t)(i * 16 + c) * 2048 + q * 8);
            bk[i] = *(const long*)(qb + 512 + (size_t)(i * 16 + c) * 2048 + q * 8);
        }

        // S = Q K^T (fp8, K=32 in one MFMA per tile pair)
        f32x4_t s[4][4];
#pragma unroll
        for (int i = 0; i < 4; ++i)
#pragma unroll
            for (int j = 0; j < 4; ++j)
                s[i][j] = __builtin_amdgcn_mfma_f32_16x16x32_fp8_fp8(aq[i], bk[j],
                          (f32x4_t){0.f, 0.f, 0.f, 0.f}, 0, 0, 0);

        // V^T -> LDS (row d, offset m*2 XOR (d&7)<<4)
#pragma unroll
        for (int l = 0; l < 4; ++l)
#pragma unroll
            for (int j = 0; j < 8; ++j) {
                const int d = l * 8 + j;
                *(bf16*)(vw + d * 128 + ((lane * 2) ^ ((d & 7) << 4))) = vrow[l][j];
            }

        // scale (incl. 1/(32*32) fp8 descale) + rel-pos bias + row softmax
        const float scale = 0.17677669529663687f / 1024.0f;
        float inv[4][4];
#pragma unroll
        for (int i = 0; i < 4; ++i)
#pragma unroll
            for (int jj = 0; jj < 4; ++jj) {
                const int n = i * 16 + q * 4 + jj;
                const int na = n >> 3, nu = n & 7;
                float mx = -1e30f;
#pragma unroll
                for (int j = 0; j < 4; ++j) {
                    const int m = j * 16 + c;
                    const int idx = (na - (m >> 3) + 7) * 15 + (nu - (m & 7) + 7);
                    float v = s[i][j][jj] * scale + ptl[head][idx];
                    s[i][j][jj] = v;
                    mx = fmaxf(mx, v);
                }
#pragma unroll
                for (int off = 1; off < 16; off <<= 1) mx = fmaxf(mx, __shfl_xor(mx, off));
                float sum = 0.f;
#pragma unroll
                for (int j = 0; j < 4; ++j) {
                    float e = __expf(s[i][j][jj] - mx);
                    s[i][j][jj] = e; sum += e;
                }
#pragma unroll
                for (int off = 1; off < 16; off <<= 1) sum += __shfl_xor(sum, off);
                inv[i][jj] = 1.0f / sum;
            }

        // P -> LDS (bf16, swizzled: byte ^= (row&7)<<4)
#pragma unroll
        for (int i = 0; i < 4; ++i)
#pragma unroll
            for (int jj = 0; jj < 4; ++jj) {
                const int n = i * 16 + q * 4 + jj;
                const int swz = (n & 7) << 4;
#pragma unroll
                for (int j = 0; j < 4; ++j) {
                    const int m = j * 16 + c;
                    *(bf16*)((char*)pw + n * 128 + ((m * 2) ^ swz)) = (bf16)s[i][j][jj];
                }
            }

        // V B-frags from LDS V^T
        bf16x8 bv[2][2];
#pragma unroll
        for (int ks = 0; ks < 2; ++ks)
#pragma unroll
            for (int dt = 0; dt < 2; ++dt)
                bv[ks][dt] = *(const bf16x8*)(vw + (dt * 16 + c) * 128 +
                              ((ks * 64 + q * 16) ^ ((c & 7) << 4)));

        // O = P V (bf16)
        f32x4_t o[4][2];
#pragma unroll
        for (int i = 0; i < 4; ++i)
#pragma unroll
            for (int dt = 0; dt < 2; ++dt)
                o[i][dt] = (f32x4_t){0.f, 0.f, 0.f, 0.f};
#pragma unroll
        for (int ks = 0; ks < 2; ++ks)
#pragma unroll
            for (int i = 0; i < 4; ++i) {
                const int n = i * 16 + c;
                bf16x8 ap = *(const bf16x8*)((char*)pw + n * 128 +
                             ((ks * 64 + q * 16) ^ ((n & 7) << 4)));
#pragma unroll
                for (int dt = 0; dt < 2; ++dt)
                    o[i][dt] = __builtin_amdgcn_mfma_f32_16x16x32_bf16(ap, bv[ks][dt], o[i][dt], 0, 0, 0);
            }

        // normalize + store fp8 x32
        unsigned char* ob = obuf + rowb * 512 + head * 32;
#pragma unroll
        for (int i = 0; i < 4; ++i)
#pragma unroll
            for (int dt = 0; dt < 2; ++dt)
#pragma unroll
                for (int jj = 0; jj < 4; ++jj) {
                    const int n = i * 16 + q * 4 + jj;
                    float val = o[i][dt][jj] * inv[i][jj] * 32.0f;
                    int p8 = __builtin_amdgcn_cvt_pk_fp8_f32(val, val, 0, false);
                    ob[(size_t)n * 512 + dt * 16 + c] = (unsigned char)(p8 & 0xff);
                }
    }
}

// ---------------- fp8 GEMM, COMPILE-TIME K: C = A*B^T*invs + bias, epilogues ----------------
// K templated -> kt loop fully unrolls: per-lane stage addresses computed ONCE,
// later tiles are base+constant; LDS read offsets loop-invariant.
// FIX vs R16: logical slot step is 2 per MFMA K-step (32 B = 2 x 16 B slots):
//   sbo[kk] = (((2*kk + (q>>1)) ^ key) << 4) + hb8   [R16 wrongly used kk + (q>>1)]
// BK=128, 32 KiB LDS, slot swizzle key=row&7, R7-proven vmcnt(0)+syncthreads pair.
// MODE 0: QKV mixed out | 1: gelu->fp8 (MLP1) | 2: +resid ungroup f32 (proj) | 3: +resid f32 (MLP2)
template<int MODE, int NBX, int K>
__global__ __launch_bounds__(256, 2)
void gemm_fp8(const unsigned char* __restrict__ A, const unsigned char* __restrict__ Bw,
              const float* __restrict__ bias, const float* __restrict__ resid,
              void* __restrict__ outp, int N, float invs)
{
    __shared__ alignas(16) unsigned char As[128 * 128];  // 16 KiB
    __shared__ alignas(16) unsigned char Bs[128 * 128];  // 16 KiB
    const int tid = threadIdx.x;
    const int lane = tid & 63;
    const int w = tid >> 6;
    const int wr = w >> 1, wc = w & 1;
    const int c = lane & 15, q = lane >> 4;

    const int bid = blockIdx.y * NBX + blockIdx.x;
    const int nwg = gridDim.y * NBX;
    const int swz = (bid & 7) * (nwg >> 3) + (bid >> 3);
    const int by = swz / NBX;
    const int bx = swz - by * NBX;
    const int rowBase = by * 128;
    const int colBase = bx * 128;

    f32x4_t acc[4][4];
#pragma unroll
    for (int m = 0; m < 4; ++m)
#pragma unroll
        for (int n = 0; n < 4; ++n)
            acc[m][n] = (f32x4_t){0.f, 0.f, 0.f, 0.f};

    const int key = c & 7;               // row&7 for rows ...*16 + c
    const int hb8 = (q & 1) * 8;

    // per-lane stage base addresses (computed once; kt adds a compile-time constant)
    const unsigned char* aSrc[4];
    const unsigned char* bSrc[4];
    int ldsOff[4];
#pragma unroll
    for (int l = 0; l < 4; ++l) {
        const int cg = l * 256 + tid;
        const int row = cg >> 3;
        const int sg = (cg & 7) ^ (row & 7);
        aSrc[l] = A + (size_t)(rowBase + row) * K + sg * 16;
        bSrc[l] = Bw + (size_t)(colBase + row) * K + sg * 16;
        ldsOff[l] = (l * 256 + (tid & 192)) * 16;
    }
    // loop-invariant LDS read byte offsets: kk-th MFMA step covers logical slots
    // {2kk, 2kk+1}; lane's logical slot = 2kk + (q>>1), physical = logical ^ key
    int sbo[4];
#pragma unroll
    for (int kk = 0; kk < 4; ++kk)
        sbo[kk] = (((2 * kk + (q >> 1)) ^ key) << 4) + hb8;

#pragma unroll
    for (int kt = 0; kt < K; kt += 128) {
#pragma unroll
        for (int l = 0; l < 4; ++l) {
            ASYNC_COPY16(aSrc[l] + kt, As + ldsOff[l]);
            ASYNC_COPY16(bSrc[l] + kt, Bs + ldsOff[l]);
        }
        WAITV0();
        __syncthreads();
#pragma unroll
        for (int kk = 0; kk < 4; ++kk) {
            const int sb = sbo[kk];
            long af[4], bfr[4];
#pragma unroll
            for (int m = 0; m < 4; ++m) {
                const int row = wr * 64 + m * 16 + c;
                af[m] = *(const long*)((const char*)As + row * 128 + sb);
            }
#pragma unroll
            for (int n = 0; n < 4; ++n) {
                const int row = wc * 64 + n * 16 + c;
                bfr[n] = *(const long*)((const char*)Bs + row * 128 + sb);
            }
#pragma unroll
            for (int m = 0; m < 4; ++m)
#pragma unroll
                for (int n = 0; n < 4; ++n)
                    acc[m][n] = __builtin_amdgcn_mfma_f32_16x16x32_fp8_fp8(af[m], bfr[n], acc[m][n], 0, 0, 0);
        }
        __syncthreads();
    }

#pragma unroll
    for (int m = 0; m < 4; ++m) {
#pragma unroll
        for (int jj = 0; jj < 4; ++jj) {
            int grow = rowBase + wr * 64 + m * 16 + q * 4 + jj;
#pragma unroll
            for (int n = 0; n < 4; ++n) {
                int gcol = colBase + wc * 64 + n * 16 + c;
                float v = acc[m][n][jj] * invs + bias[gcol];
                if constexpr (MODE == 0) {
                    char* ob = (char*)outp;
                    if (gcol < 1024) {   // Q/K: fp8 x32 (tile-uniform branch)
                        int p8 = __builtin_amdgcn_cvt_pk_fp8_f32(v * 32.0f, v * 32.0f, 0, false);
                        ob[(size_t)grow * 2048 + gcol] = (char)(p8 & 0xff);
                    } else {             // V: bf16
                        *(bf16*)(ob + (size_t)grow * 2048 + 1024 + (size_t)(gcol - 1024) * 2) = (bf16)v;
                    }
                } else if constexpr (MODE == 1) {
                    float e = __expf(1.5957691216057308f * (v + 0.044715f * v * v * v));
                    v = v * (e / (1.0f + e));
                    int p8 = __builtin_amdgcn_cvt_pk_fp8_f32(v * 64.0f, v * 64.0f, 0, false);
                    ((unsigned char*)outp)[(size_t)grow * N + gcol] = (unsigned char)(p8 & 0xff);
                } else if constexpr (MODE == 2) {
                    int g = grow >> 6, ns = grow & 63;
                    int b = g >> 6, i = (g >> 3) & 7, j = g & 7;
                    int a = ns >> 3, u = ns & 7;
                    int t = b * 4096 + (a * 8 + i) * 64 + (u * 8 + j);
                    size_t oi = (size_t)t * 512 + gcol;
                    ((float*)outp)[oi] = resid[oi] + v;
                } else {
                    size_t oi = (size_t)grow * 512 + gcol;
                    ((float*)outp)[oi] = resid[oi] + v;
                }
            }
        }
    }
}

// ---------------- launcher ----------------
extern "C" void kernel_launch(void* const* d_in, const int* in_sizes, int n_in,
                              void* d_out, int out_size, void* d_ws, size_t ws_size,
                              hipStream_t stream)
{
    const float* x    = (const float*)d_in[0];
    const float* n1g  = (const float*)d_in[1];
    const float* n1b  = (const float*)d_in[2];
    const float* qkvw = (const float*)d_in[3];
    const float* qkvb = (const float*)d_in[4];
    const float* pjw  = (const float*)d_in[5];
    const float* pjb  = (const float*)d_in[6];
    const float* pw0  = (const float*)d_in[7];
    const float* pb0  = (const float*)d_in[8];
    const float* pg0  = (const float*)d_in[9];
    const float* pbb0 = (const float*)d_in[10];
    const float* pw1  = (const float*)d_in[11];
    const float* pb1  = (const float*)d_in[12];
    const float* pg1  = (const float*)d_in[13];
    const float* pbb1 = (const float*)d_in[14];
    const float* pw2  = (const float*)d_in[15];
    const float* pb2  = (const float*)d_in[16];
    const float* pg2  = (const float*)d_in[17];
    const float* pbb2 = (const float*)d_in[18];
    const float* pw3  = (const float*)d_in[19];
    const float* pb3  = (const float*)d_in[20];
    const float* n2g  = (const float*)d_in[21];
    const float* n2b  = (const float*)d_in[22];
    const float* w1   = (const float*)d_in[23];
    const float* b1   = (const float*)d_in[24];
    const float* w2   = (const float*)d_in[25];
    const float* b2   = (const float*)d_in[26];

    char* ws = (char*)d_ws;
    unsigned char* qkvw_f8 = (unsigned char*)(ws + OFF_QKVW);
    unsigned char* pjw_f8  = (unsigned char*)(ws + OFF_PROJW);
    unsigned char* w1_f8 = (unsigned char*)(ws + OFF_W1);
    unsigned char* w2_f8 = (unsigned char*)(ws + OFF_W2);
    float* ptab  = (float*)(ws + OFF_PTAB);
    unsigned char* bufA8 = (unsigned char*)(ws + OFF_A);   // qkv mixed / hidden fp8
    unsigned char* bufB8 = (unsigned char*)(ws + OFF_B);   // LN outs fp8 / attn-out fp8
    float* xout  = (float*)d_out;

    // weight casts (all fp8 x64)
    cast_fp8_k<<<(1536 * 512 / 4 + 255) / 256, 256, 0, stream>>>(qkvw, qkvw_f8, 1536 * 512 / 4);
    cast_fp8_k<<<(512 * 512 / 4 + 255) / 256, 256, 0, stream>>>(pjw, pjw_f8, 512 * 512 / 4);
    cast_fp8_k<<<(2048 * 512 / 4 + 255) / 256, 256, 0, stream>>>(w1, w1_f8, 2048 * 512 / 4);
    cast_fp8_k<<<(512 * 2048 / 4 + 255) / 256, 256, 0, stream>>>(w2, w2_f8, 512 * 2048 / 4);

    // pos-bias table
    posmlp_k<<<1, 256, 0, stream>>>(pw0, pb0, pg0, pbb0, pw1, pb1, pg1, pbb1,
                                    pw2, pb2, pg2, pbb2, pw3, pb3, ptab);

    // LN1 + group -> bufB (fp8 x32)
    ln_k<1><<<16384, 256, 0, stream>>>(x, n1g, n1b, bufB8);

    // QKV (fp8) -> bufA mixed layout [Qf8|Kf8|Vbf16], row stride 2048 B; invs = 1/(32*64)
    gemm_fp8<0, 12, 512><<<dim3(12, 512), 256, 0, stream>>>(bufB8, qkvw_f8, qkvb, nullptr,
                                                            bufA8, 1536, 1.0f / 2048.0f);

    // attention -> bufB (fp8 x32)
    attn_mfma_k<<<2048, 256, 0, stream>>>(bufA8, ptab, bufB8);

    // proj (fp8) + ungroup + residual(x) -> d_out (x1); invs = 1/(32*64)
    gemm_fp8<2, 4, 512><<<dim3(4, 512), 256, 0, stream>>>(bufB8, pjw_f8, pjb, x,
                                                          xout, 512, 1.0f / 2048.0f);

    // LN2 -> bufB (fp8 x32)
    ln_k<0><<<16384, 256, 0, stream>>>(xout, n2g, n2b, bufB8);

    // MLP1 (fp8) + gelu -> bufA as fp8 x64; invs = 1/(32*64)
    gemm_fp8<1, 16, 512><<<dim3(16, 512), 256, 0, stream>>>(bufB8, w1_f8, b1, nullptr,
                                                            bufA8, 2048, 1.0f / 2048.0f);

    // MLP2 (fp8) + residual(x1) -> d_out (in place); invs = 1/(64*64)
    gemm_fp8<3, 4, 2048><<<dim3(4, 512), 256, 0, stream>>>(bufA8, w2_f8, b2, xout,
                                                           xout, 512, 1.0f / 4096.0f);
}